// Round 1
// baseline (2126.194 us; speedup 1.0000x reference)
//
#include <hip/hip_runtime.h>
#include <math.h>

#define DN 8
#define CAT_K 134
#define HID1 128
#define OUT1 16
#define TILE_E 64
#define CAT_STRIDE 140   // 140 % 32 == 12 -> conflict-free a-loads
#define HIDS 129         // 129 % 32 == 1  -> 2-way (free) phase-3 reads

__device__ __forceinline__ float silu(float x) {
    return x / (1.0f + __expf(-x));
}

// ---------------------------------------------------------------------------
// Kernel 1: per-edge MLP (134->128->16, SiLU) + atomic scatter-add to agg[N,16]
// ---------------------------------------------------------------------------
__global__ __launch_bounds__(256, 1)
void k_edge(const float* __restrict__ h_i,
            const float* __restrict__ node_params,
            const float* __restrict__ edge_params,
            const float* __restrict__ W1, const float* __restrict__ b1,
            const float* __restrict__ W2, const float* __restrict__ b2,
            const int* __restrict__ eidx,   // flat [2*E]: [sender | receiver]
            float* __restrict__ agg,
            int N, int E)
{
    __shared__ float W1s[CAT_K * HID1];          // 68608 B
    __shared__ float W2s[HID1 * OUT1];           //  8192 B
    __shared__ float b1s[HID1];
    __shared__ float b2s[OUT1];
    __shared__ float cat[TILE_E * CAT_STRIDE];   // 35840 B ; reused as hid[64*129]

    const int t = threadIdx.x;

    // stage weights once per block
    for (int i = t; i < CAT_K * HID1 / 4; i += 256)
        ((float4*)W1s)[i] = ((const float4*)W1)[i];
    for (int i = t; i < HID1 * OUT1 / 4; i += 256)
        ((float4*)W2s)[i] = ((const float4*)W2)[i];
    if (t < HID1) b1s[t] = b1[t];
    if (t < OUT1) b2s[t] = b2[t];

    const int nTiles = (E + TILE_E - 1) / TILE_E;
    for (int tile = blockIdx.x; tile < nTiles; tile += gridDim.x) {
        const int ebase = tile * TILE_E;

        // ---- phase 1: stage cat tile (64 x 134) ----
        {
            const int el = t >> 2;                  // 0..63
            const int p  = t & 3;                   // 0..3
            const int eg = ebase + el;
            const int egc = (eg < E) ? eg : (E - 1);
            const int s = eidx[egc];
            const int r = eidx[E + egc];
            const float4* hs = (const float4*)(h_i + (size_t)s * 64);
            const float4* hr = (const float4*)(h_i + (size_t)r * 64);
            float4* crow = (float4*)(cat + el * CAT_STRIDE);
            #pragma unroll
            for (int m = 0; m < 8; ++m) {
                int q = p + 4 * m;                  // 0..31 float4 slots
                float4 v = (q < 16) ? hs[q] : hr[q - 16];
                crow[q] = v;
            }
            if (p == 0) {
                cat[el * CAT_STRIDE + 128] = node_params[2 * s];
                cat[el * CAT_STRIDE + 129] = node_params[2 * s + 1];
            } else if (p == 1) {
                cat[el * CAT_STRIDE + 130] = node_params[2 * r];
                cat[el * CAT_STRIDE + 131] = node_params[2 * r + 1];
            } else if (p == 2) {
                // faithful edge_params[edge_index].reshape(E,-1):
                // ep[e][c] = edge_params[ eidx_flat[2e + c] ]
                int i0 = eidx[2 * egc];
                int i1 = eidx[2 * egc + 1];
                cat[el * CAT_STRIDE + 132] = edge_params[i0];
                cat[el * CAT_STRIDE + 133] = edge_params[i1];
            }
        }
        __syncthreads();

        // ---- phase 2: hidden = silu(cat @ W1 + b1) ----
        const int tx = t & 15;     // output group: j = tx*8 .. tx*8+7
        const int ty = t >> 4;     // 0..15 : edges {ty, ty+16, ty+32, ty+48}
        float acc[4][8];
        #pragma unroll
        for (int i = 0; i < 4; ++i)
            #pragma unroll
            for (int j = 0; j < 8; ++j) acc[i][j] = 0.0f;

        #pragma unroll 2
        for (int k = 0; k < CAT_K; ++k) {
            const float4 w0 = *(const float4*)&W1s[k * HID1 + tx * 8];
            const float4 w1 = *(const float4*)&W1s[k * HID1 + tx * 8 + 4];
            float a[4];
            #pragma unroll
            for (int i = 0; i < 4; ++i)
                a[i] = cat[(ty + 16 * i) * CAT_STRIDE + k];
            #pragma unroll
            for (int i = 0; i < 4; ++i) {
                acc[i][0] += a[i] * w0.x;  acc[i][1] += a[i] * w0.y;
                acc[i][2] += a[i] * w0.z;  acc[i][3] += a[i] * w0.w;
                acc[i][4] += a[i] * w1.x;  acc[i][5] += a[i] * w1.y;
                acc[i][6] += a[i] * w1.z;  acc[i][7] += a[i] * w1.w;
            }
        }
        __syncthreads();   // all cat reads done; safe to overwrite with hid

        float* hid = cat;  // reuse buffer, stride HIDS
        #pragma unroll
        for (int i = 0; i < 4; ++i) {
            const int e = ty + 16 * i;
            #pragma unroll
            for (int j = 0; j < 8; ++j) {
                float x = acc[i][j] + b1s[tx * 8 + j];
                hid[e * HIDS + tx * 8 + j] = silu(x);
            }
        }
        __syncthreads();

        // ---- phase 3: I = silu(hid @ W2 + b2); scatter-add ----
        {
            const int e  = t & 63;
            const int og = t >> 6;   // 0..3 -> outputs og*4 .. og*4+3
            float a2[4] = {0.f, 0.f, 0.f, 0.f};
            #pragma unroll 4
            for (int k = 0; k < HID1; ++k) {
                const float h = hid[e * HIDS + k];
                const float4 w = *(const float4*)&W2s[k * OUT1 + og * 4];
                a2[0] += h * w.x; a2[1] += h * w.y;
                a2[2] += h * w.z; a2[3] += h * w.w;
            }
            const int eg = ebase + e;
            if (eg < E) {
                const int r = eidx[E + eg];
                #pragma unroll
                for (int oo = 0; oo < 4; ++oo) {
                    float v = silu(a2[oo] + b2s[og * 4 + oo]);
                    atomicAdd(&agg[(size_t)r * 16 + og * 4 + oo], v);
                }
            }
        }
        __syncthreads();   // before next tile overwrites cat
    }
}

// ---------------------------------------------------------------------------
// Kernel 2: per-node Jacobi eigh + node MLP + softmax + V diag(lam) V^T
// ---------------------------------------------------------------------------
template <int P, int Q>
__device__ __forceinline__ void jrot(float* A, float* V) {
    const float app = A[P * 8 + P];
    const float aqq = A[Q * 8 + Q];
    const float apq = A[P * 8 + Q];
    const float absq = fabsf(apq);

    float theta = (aqq - app) / (2.0f * apq);
    float at = fabsf(theta);
    float tt = 1.0f / (at + sqrtf(at * at + 1.0f));
    tt = (theta < 0.0f) ? -tt : tt;
    float cc = __frsqrt_rn(tt * tt + 1.0f);
    float ss = tt * cc;

    const bool skip = !(absq > 1e-36f);
    const float c = skip ? 1.0f : cc;
    const float s = skip ? 0.0f : ss;

    // rows P,Q  (J^T * A)
    #pragma unroll
    for (int k = 0; k < 8; ++k) {
        float ap = A[P * 8 + k], aq = A[Q * 8 + k];
        A[P * 8 + k] = c * ap - s * aq;
        A[Q * 8 + k] = s * ap + c * aq;
    }
    // cols P,Q  ((J^T A) * J)
    #pragma unroll
    for (int k = 0; k < 8; ++k) {
        float ap = A[k * 8 + P], aq = A[k * 8 + Q];
        A[k * 8 + P] = c * ap - s * aq;
        A[k * 8 + Q] = s * ap + c * aq;
    }
    // V = V * J
    #pragma unroll
    for (int k = 0; k < 8; ++k) {
        float vp = V[k * 8 + P], vq = V[k * 8 + Q];
        V[k * 8 + P] = c * vp - s * vq;
        V[k * 8 + Q] = s * vp + c * vq;
    }
}

__device__ __forceinline__ void jacobi_sweep(float* A, float* V) {
    jrot<0,1>(A,V); jrot<0,2>(A,V); jrot<0,3>(A,V); jrot<0,4>(A,V);
    jrot<0,5>(A,V); jrot<0,6>(A,V); jrot<0,7>(A,V);
    jrot<1,2>(A,V); jrot<1,3>(A,V); jrot<1,4>(A,V); jrot<1,5>(A,V);
    jrot<1,6>(A,V); jrot<1,7>(A,V);
    jrot<2,3>(A,V); jrot<2,4>(A,V); jrot<2,5>(A,V); jrot<2,6>(A,V);
    jrot<2,7>(A,V);
    jrot<3,4>(A,V); jrot<3,5>(A,V); jrot<3,6>(A,V); jrot<3,7>(A,V);
    jrot<4,5>(A,V); jrot<4,6>(A,V); jrot<4,7>(A,V);
    jrot<5,6>(A,V); jrot<5,7>(A,V);
    jrot<6,7>(A,V);
}

#define CSWAP(a, b)                                                          \
    {                                                                        \
        bool sw = eig[a] > eig[b];                                           \
        float lo = sw ? eig[b] : eig[a];                                     \
        float hi = sw ? eig[a] : eig[b];                                     \
        eig[a] = lo; eig[b] = hi;                                            \
        _Pragma("unroll")                                                    \
        for (int k = 0; k < 8; ++k) {                                        \
            float va = V[k * 8 + a], vb = V[k * 8 + b];                      \
            V[k * 8 + a] = sw ? vb : va;                                     \
            V[k * 8 + b] = sw ? va : vb;                                     \
        }                                                                    \
    }

__global__ __launch_bounds__(256)
void k_node(const float* __restrict__ h_i,
            const float* __restrict__ agg,
            const float* __restrict__ W3, const float* __restrict__ b3,
            const float* __restrict__ W4, const float* __restrict__ b4,
            float* __restrict__ out, int N)
{
    const int n = blockIdx.x * 256 + threadIdx.x;
    if (n >= N) return;

    float A[64], V[64];
    {
        const float4* src = (const float4*)(h_i + (size_t)n * 64);
        #pragma unroll
        for (int i = 0; i < 16; ++i) ((float4*)A)[i] = src[i];
    }
    #pragma unroll
    for (int i = 0; i < 64; ++i) V[i] = 0.0f;
    #pragma unroll
    for (int i = 0; i < 8; ++i) V[i * 8 + i] = 1.0f;

    #pragma unroll 1
    for (int sw = 0; sw < 7; ++sw) jacobi_sweep(A, V);

    float eig[8];
    #pragma unroll
    for (int i = 0; i < 8; ++i) eig[i] = A[i * 8 + i];

    // Batcher odd-even mergesort (ascending), swap V columns along
    CSWAP(0,1) CSWAP(2,3) CSWAP(4,5) CSWAP(6,7)
    CSWAP(0,2) CSWAP(1,3) CSWAP(4,6) CSWAP(5,7)
    CSWAP(1,2) CSWAP(5,6)
    CSWAP(0,4) CSWAP(1,5) CSWAP(2,6) CSWAP(3,7)
    CSWAP(2,4) CSWAP(3,5)
    CSWAP(1,2) CSWAP(3,4) CSWAP(5,6)

    // feats = [agg(16) | eig(8) | row-norms of V (8)]
    float f[32];
    {
        const float4* ag = (const float4*)(agg + (size_t)n * 16);
        #pragma unroll
        for (int i = 0; i < 4; ++i) {
            float4 v = ag[i];
            f[i * 4 + 0] = v.x; f[i * 4 + 1] = v.y;
            f[i * 4 + 2] = v.z; f[i * 4 + 3] = v.w;
        }
    }
    #pragma unroll
    for (int i = 0; i < 8; ++i) f[16 + i] = eig[i];
    #pragma unroll
    for (int i = 0; i < 8; ++i) {
        float sum = 0.0f;
        #pragma unroll
        for (int j = 0; j < 8; ++j) sum += V[i * 8 + j] * V[i * 8 + j];
        f[24 + i] = sqrtf(sum);
    }

    // node MLP: z = silu(f @ W3 + b3) @ W4 + b4  (W3/W4 reads are wave-uniform)
    float z[8];
    #pragma unroll
    for (int o = 0; o < 8; ++o) z[o] = b4[o];
    #pragma unroll 1
    for (int j = 0; j < 128; ++j) {
        float h = b3[j];
        #pragma unroll
        for (int k = 0; k < 32; ++k) h += f[k] * W3[k * 128 + j];
        float sv = silu(h);
        #pragma unroll
        for (int o = 0; o < 8; ++o) z[o] += sv * W4[j * 8 + o];
    }

    // softmax
    float m = z[0];
    #pragma unroll
    for (int o = 1; o < 8; ++o) m = fmaxf(m, z[o]);
    float lam[8], den = 0.0f;
    #pragma unroll
    for (int o = 0; o < 8; ++o) { lam[o] = __expf(z[o] - m); den += lam[o]; }
    const float inv = 1.0f / den;
    #pragma unroll
    for (int o = 0; o < 8; ++o) lam[o] *= inv;

    // out[i][k] = sum_j lam[j] * V[i][j] * V[k][j]
    float S[64];
    #pragma unroll
    for (int i = 0; i < 8; ++i)
        #pragma unroll
        for (int j = 0; j < 8; ++j) S[i * 8 + j] = lam[j] * V[i * 8 + j];

    float* orow = out + (size_t)n * 64;
    #pragma unroll
    for (int i = 0; i < 8; ++i) {
        float r[8];
        #pragma unroll
        for (int k = 0; k < 8; ++k) {
            float sum = 0.0f;
            #pragma unroll
            for (int j = 0; j < 8; ++j) sum += S[i * 8 + j] * V[k * 8 + j];
            r[k] = sum;
        }
        ((float4*)orow)[i * 2 + 0] = make_float4(r[0], r[1], r[2], r[3]);
        ((float4*)orow)[i * 2 + 1] = make_float4(r[4], r[5], r[6], r[7]);
    }
}

// ---------------------------------------------------------------------------
extern "C" void kernel_launch(void* const* d_in, const int* in_sizes, int n_in,
                              void* d_out, int out_size, void* d_ws, size_t ws_size,
                              hipStream_t stream) {
    const float* h_i  = (const float*)d_in[0];
    const float* npar = (const float*)d_in[1];
    const float* epar = (const float*)d_in[2];
    const float* W1   = (const float*)d_in[3];
    const float* b1   = (const float*)d_in[4];
    const float* W2   = (const float*)d_in[5];
    const float* b2   = (const float*)d_in[6];
    const float* W3   = (const float*)d_in[7];
    const float* b3   = (const float*)d_in[8];
    const float* W4   = (const float*)d_in[9];
    const float* b4   = (const float*)d_in[10];
    const int*   eidx = (const int*)d_in[11];

    const int N = in_sizes[0] / 64;
    const int E = in_sizes[11] / 2;

    float* agg = (float*)d_ws;
    hipMemsetAsync(agg, 0, (size_t)N * 16 * sizeof(float), stream);

    k_edge<<<2048, 256, 0, stream>>>(h_i, npar, epar, W1, b1, W2, b2,
                                     eidx, agg, N, E);
    k_node<<<(N + 255) / 256, 256, 0, stream>>>(h_i, agg, W3, b3, W4, b4,
                                                (float*)d_out, N);
}

// Round 2
// 681.961 us; speedup vs baseline: 3.1178x; 3.1178x over previous
//
#include <hip/hip_runtime.h>
#include <math.h>

#define HID1 128
#define OUT1 16
#define TILE_E 64
#define CATS 168        // cat/W1t row stride (bf16): 84 dw % 32 = 20 -> 2-way, free
#define HS   136        // hid/W2t row stride (bf16): 68 dw % 32 = 4  -> 2-way, free
#define KPAD 160        // 134 padded to 5 k-steps of 32

typedef __attribute__((ext_vector_type(8))) short bf16x8;
typedef __attribute__((ext_vector_type(4))) float f32x4;

__device__ __forceinline__ float silu(float x) {
    return x / (1.0f + __expf(-x));
}

__device__ __forceinline__ unsigned short f2bf(float x) {
    union { float f; unsigned u; } v; v.f = x;
    unsigned r = v.u + 0x7fffu + ((v.u >> 16) & 1u);   // RNE
    return (unsigned short)(r >> 16);
}

__device__ __forceinline__ unsigned pack2(float a, float b) {
    return (unsigned)f2bf(a) | ((unsigned)f2bf(b) << 16);
}

// ---------------------------------------------------------------------------
// Kernel 1: per-edge MLP via bf16 MFMA + atomic scatter-add to agg[N,16]
//   layer1: cat[64x160] @ W1t -> hid[64x128]   (40 MFMA/wave/tile)
//   layer2: hid[64x128] @ W2t -> I[64x16]      ( 4 MFMA/wave/tile)
// ---------------------------------------------------------------------------
__global__ __launch_bounds__(256, 2)
void k_edge(const float* __restrict__ h_i,
            const float* __restrict__ node_params,
            const float* __restrict__ edge_params,
            const float* __restrict__ W1, const float* __restrict__ b1,
            const float* __restrict__ W2, const float* __restrict__ b2,
            const int* __restrict__ eidx,   // flat [2*E]: [sender | receiver]
            float* __restrict__ agg,
            int N, int E)
{
    // union layout: [ W1t 128*168 us | W2t 16*136 us ] = 23680 ushorts (47360 B)
    // after B-frag reg loads, region reused as: [ cat 64*168 | hid 64*136 ]
    __shared__ unsigned short smem[23680];
    unsigned short* w1t = smem;                  // [128][CATS]
    unsigned short* w2t = smem + 128 * CATS;     // [16][HS]
    unsigned short* cat = smem;                  // [64][CATS]
    unsigned short* hid = smem + 64 * CATS;      // [64][HS]  (fits in w1t area)

    const int t = threadIdx.x;
    const int lane = t & 63;
    const int wv = t >> 6;        // wave 0..3
    const int wn = wv & 1;        // N half (cols wn*64 .. +63)
    const int wm = wv >> 1;       // M half (edges wm*32 .. +31)
    const int lr = lane & 15;
    const int lq = lane >> 4;

    // ---- stage W1^T, W2^T into LDS as bf16 (once per block) ----
    for (int idx = t; idx < 128 * 80; idx += 256) {      // W1t[col][k], k pairs
        const int col = idx & 127, kp = idx >> 7;        // kp 0..79
        const int k0 = 2 * kp;
        float f0 = (k0     < 134) ? W1[(size_t)k0       * 128 + col] : 0.0f;
        float f1 = (k0 + 1 < 134) ? W1[(size_t)(k0 + 1) * 128 + col] : 0.0f;
        *(unsigned*)&w1t[col * CATS + k0] = pack2(f0, f1);
    }
    for (int idx = t; idx < 16 * 64; idx += 256) {       // W2t[col][k]
        const int col = idx & 15, kp = idx >> 4;         // kp 0..63
        const int k0 = 2 * kp;
        *(unsigned*)&w2t[col * HS + k0] =
            pack2(W2[(size_t)k0 * 16 + col], W2[(size_t)(k0 + 1) * 16 + col]);
    }
    __syncthreads();

    // ---- load B fragments into registers (layout: lane holds B[k][col],
    //      col = lr, k = lq*8 + j  -> read W1t[col][k...k+7] contiguous) ----
    bf16x8 bw1[4][5];
    #pragma unroll
    for (int nf = 0; nf < 4; ++nf)
        #pragma unroll
        for (int ks = 0; ks < 5; ++ks)
            bw1[nf][ks] = *(const bf16x8*)&w1t[(wn * 64 + nf * 16 + lr) * CATS + ks * 32 + lq * 8];
    bf16x8 bw2[4];
    #pragma unroll
    for (int ks = 0; ks < 4; ++ks)
        bw2[ks] = *(const bf16x8*)&w2t[lr * HS + ks * 32 + lq * 8];

    float bias1[4];
    #pragma unroll
    for (int nf = 0; nf < 4; ++nf) bias1[nf] = b1[wn * 64 + nf * 16 + lr];
    const float bias2 = b2[lr];
    __syncthreads();   // done reading w1t/w2t; region becomes cat/hid

    const int el = t >> 2;        // 0..63 (staging role)
    const int p  = t & 3;

    const int nTiles = E / TILE_E;
    for (int tile = blockIdx.x; tile < nTiles; tile += gridDim.x) {
        const int ebase = tile * TILE_E;

        // ---- stage cat tile (64 x 160 bf16) ----
        {
            const int eg  = ebase + el;
            const int egc = (eg < E) ? eg : (E - 1);
            const int s = eidx[egc];
            const int r = eidx[E + egc];
            const float4* hs = (const float4*)(h_i + (size_t)s * 64);
            const float4* hr = (const float4*)(h_i + (size_t)r * 64);
            unsigned short* crow = cat + el * CATS;
            #pragma unroll
            for (int m = 0; m < 8; ++m) {
                const int q = p + 4 * m;                  // float4 slot 0..31
                float4 v = (q < 16) ? hs[q] : hr[q - 16];
                uint2 u; u.x = pack2(v.x, v.y); u.y = pack2(v.z, v.w);
                *(uint2*)&crow[q * 4] = u;
            }
            if (p == 0) {
                // cols 128..135: np_s(2) np_r(2) ep(2) 0 0
                const int i0 = eidx[2 * egc];
                const int i1 = eidx[2 * egc + 1];
                uint4 u;
                u.x = pack2(node_params[2 * s], node_params[2 * s + 1]);
                u.y = pack2(node_params[2 * r], node_params[2 * r + 1]);
                u.z = pack2(edge_params[i0], edge_params[i1]);
                u.w = 0u;
                *(uint4*)&crow[128] = u;
            } else {
                // cols 136..159 zero pad
                uint4 z; z.x = z.y = z.z = z.w = 0u;
                *(uint4*)&crow[136 + (p - 1) * 8] = z;
            }
        }
        __syncthreads();

        // ---- layer 1 MFMA: acc[mf][nf] over 5 k-steps ----
        f32x4 acc[2][4];
        #pragma unroll
        for (int mf = 0; mf < 2; ++mf)
            #pragma unroll
            for (int nf = 0; nf < 4; ++nf)
                acc[mf][nf] = (f32x4){0.f, 0.f, 0.f, 0.f};

        const unsigned short* pa = cat + (wm * 32 + lr) * CATS + lq * 8;
        #pragma unroll
        for (int ks = 0; ks < 5; ++ks) {
            const bf16x8 a0 = *(const bf16x8*)(pa + ks * 32);
            const bf16x8 a1 = *(const bf16x8*)(pa + 16 * CATS + ks * 32);
            #pragma unroll
            for (int nf = 0; nf < 4; ++nf) {
                acc[0][nf] = __builtin_amdgcn_mfma_f32_16x16x32_bf16(a0, bw1[nf][ks], acc[0][nf], 0, 0, 0);
                acc[1][nf] = __builtin_amdgcn_mfma_f32_16x16x32_bf16(a1, bw1[nf][ks], acc[1][nf], 0, 0, 0);
            }
        }

        // bias + silu -> hid (bf16). D layout: row=lq*4+r2 (edge), col=lr (n)
        #pragma unroll
        for (int mf = 0; mf < 2; ++mf)
            #pragma unroll
            for (int nf = 0; nf < 4; ++nf) {
                const float bb = bias1[nf];
                #pragma unroll
                for (int r2 = 0; r2 < 4; ++r2) {
                    const float x = acc[mf][nf][r2] + bb;
                    hid[(wm * 32 + mf * 16 + lq * 4 + r2) * HS + wn * 64 + nf * 16 + lr] =
                        f2bf(silu(x));
                }
            }
        __syncthreads();

        // ---- layer 2 MFMA: edges wv*16..+15, all 16 outputs ----
        f32x4 acc2 = (f32x4){0.f, 0.f, 0.f, 0.f};
        const unsigned short* ph = hid + (wv * 16 + lr) * HS + lq * 8;
        #pragma unroll
        for (int ks = 0; ks < 4; ++ks)
            acc2 = __builtin_amdgcn_mfma_f32_16x16x32_bf16(
                *(const bf16x8*)(ph + ks * 32), bw2[ks], acc2, 0, 0, 0);

        // silu + scatter-add. D layout: row=lq*4+r2 (edge), col=lr (out dim)
        #pragma unroll
        for (int r2 = 0; r2 < 4; ++r2) {
            const int eg2 = ebase + wv * 16 + lq * 4 + r2;
            if (eg2 < E) {
                const int rcv = eidx[E + eg2];
                const float v = silu(acc2[r2] + bias2);
                atomicAdd(&agg[(size_t)rcv * 16 + lr], v);
            }
        }
        __syncthreads();   // protect cat/hid before next tile
    }
}

// ---------------------------------------------------------------------------
// Kernel 2: per-node Jacobi eigh + node MLP + softmax + V diag(lam) V^T
// ---------------------------------------------------------------------------
template <int P, int Q>
__device__ __forceinline__ void jrot(float* A, float* V) {
    const float app = A[P * 8 + P];
    const float aqq = A[Q * 8 + Q];
    const float apq = A[P * 8 + Q];
    const float absq = fabsf(apq);

    float theta = (aqq - app) / (2.0f * apq);
    float at = fabsf(theta);
    float tt = 1.0f / (at + sqrtf(at * at + 1.0f));
    tt = (theta < 0.0f) ? -tt : tt;
    float cc = __frsqrt_rn(tt * tt + 1.0f);
    float ss = tt * cc;

    const bool skip = !(absq > 1e-36f);
    const float c = skip ? 1.0f : cc;
    const float s = skip ? 0.0f : ss;

    #pragma unroll
    for (int k = 0; k < 8; ++k) {
        float ap = A[P * 8 + k], aq = A[Q * 8 + k];
        A[P * 8 + k] = c * ap - s * aq;
        A[Q * 8 + k] = s * ap + c * aq;
    }
    #pragma unroll
    for (int k = 0; k < 8; ++k) {
        float ap = A[k * 8 + P], aq = A[k * 8 + Q];
        A[k * 8 + P] = c * ap - s * aq;
        A[k * 8 + Q] = s * ap + c * aq;
    }
    #pragma unroll
    for (int k = 0; k < 8; ++k) {
        float vp = V[k * 8 + P], vq = V[k * 8 + Q];
        V[k * 8 + P] = c * vp - s * vq;
        V[k * 8 + Q] = s * vp + c * vq;
    }
}

__device__ __forceinline__ void jacobi_sweep(float* A, float* V) {
    jrot<0,1>(A,V); jrot<0,2>(A,V); jrot<0,3>(A,V); jrot<0,4>(A,V);
    jrot<0,5>(A,V); jrot<0,6>(A,V); jrot<0,7>(A,V);
    jrot<1,2>(A,V); jrot<1,3>(A,V); jrot<1,4>(A,V); jrot<1,5>(A,V);
    jrot<1,6>(A,V); jrot<1,7>(A,V);
    jrot<2,3>(A,V); jrot<2,4>(A,V); jrot<2,5>(A,V); jrot<2,6>(A,V);
    jrot<2,7>(A,V);
    jrot<3,4>(A,V); jrot<3,5>(A,V); jrot<3,6>(A,V); jrot<3,7>(A,V);
    jrot<4,5>(A,V); jrot<4,6>(A,V); jrot<4,7>(A,V);
    jrot<5,6>(A,V); jrot<5,7>(A,V);
    jrot<6,7>(A,V);
}

#define CSWAP(a, b)                                                          \
    {                                                                        \
        bool sw = eig[a] > eig[b];                                           \
        float lo = sw ? eig[b] : eig[a];                                     \
        float hi = sw ? eig[a] : eig[b];                                     \
        eig[a] = lo; eig[b] = hi;                                            \
        _Pragma("unroll")                                                    \
        for (int k = 0; k < 8; ++k) {                                        \
            float va = V[k * 8 + a], vb = V[k * 8 + b];                      \
            V[k * 8 + a] = sw ? vb : va;                                     \
            V[k * 8 + b] = sw ? va : vb;                                     \
        }                                                                    \
    }

__global__ __launch_bounds__(256)
void k_node(const float* __restrict__ h_i,
            const float* __restrict__ agg,
            const float* __restrict__ W3, const float* __restrict__ b3,
            const float* __restrict__ W4, const float* __restrict__ b4,
            float* __restrict__ out, int N)
{
    const int n = blockIdx.x * 256 + threadIdx.x;
    if (n >= N) return;

    float A[64], V[64];
    {
        const float4* src = (const float4*)(h_i + (size_t)n * 64);
        #pragma unroll
        for (int i = 0; i < 16; ++i) ((float4*)A)[i] = src[i];
    }
    #pragma unroll
    for (int i = 0; i < 64; ++i) V[i] = 0.0f;
    #pragma unroll
    for (int i = 0; i < 8; ++i) V[i * 8 + i] = 1.0f;

    #pragma unroll 1
    for (int sw = 0; sw < 7; ++sw) jacobi_sweep(A, V);

    float eig[8];
    #pragma unroll
    for (int i = 0; i < 8; ++i) eig[i] = A[i * 8 + i];

    CSWAP(0,1) CSWAP(2,3) CSWAP(4,5) CSWAP(6,7)
    CSWAP(0,2) CSWAP(1,3) CSWAP(4,6) CSWAP(5,7)
    CSWAP(1,2) CSWAP(5,6)
    CSWAP(0,4) CSWAP(1,5) CSWAP(2,6) CSWAP(3,7)
    CSWAP(2,4) CSWAP(3,5)
    CSWAP(1,2) CSWAP(3,4) CSWAP(5,6)

    float f[32];
    {
        const float4* ag = (const float4*)(agg + (size_t)n * 16);
        #pragma unroll
        for (int i = 0; i < 4; ++i) {
            float4 v = ag[i];
            f[i * 4 + 0] = v.x; f[i * 4 + 1] = v.y;
            f[i * 4 + 2] = v.z; f[i * 4 + 3] = v.w;
        }
    }
    #pragma unroll
    for (int i = 0; i < 8; ++i) f[16 + i] = eig[i];
    #pragma unroll
    for (int i = 0; i < 8; ++i) {
        float sum = 0.0f;
        #pragma unroll
        for (int j = 0; j < 8; ++j) sum += V[i * 8 + j] * V[i * 8 + j];
        f[24 + i] = sqrtf(sum);
    }

    float z[8];
    #pragma unroll
    for (int o = 0; o < 8; ++o) z[o] = b4[o];
    #pragma unroll 1
    for (int j = 0; j < 128; ++j) {
        float h = b3[j];
        #pragma unroll
        for (int k = 0; k < 32; ++k) h += f[k] * W3[k * 128 + j];
        float sv = silu(h);
        #pragma unroll
        for (int o = 0; o < 8; ++o) z[o] += sv * W4[j * 8 + o];
    }

    float m = z[0];
    #pragma unroll
    for (int o = 1; o < 8; ++o) m = fmaxf(m, z[o]);
    float lam[8], den = 0.0f;
    #pragma unroll
    for (int o = 0; o < 8; ++o) { lam[o] = __expf(z[o] - m); den += lam[o]; }
    const float inv = 1.0f / den;
    #pragma unroll
    for (int o = 0; o < 8; ++o) lam[o] *= inv;

    float S[64];
    #pragma unroll
    for (int i = 0; i < 8; ++i)
        #pragma unroll
        for (int j = 0; j < 8; ++j) S[i * 8 + j] = lam[j] * V[i * 8 + j];

    float* orow = out + (size_t)n * 64;
    #pragma unroll
    for (int i = 0; i < 8; ++i) {
        float r[8];
        #pragma unroll
        for (int k = 0; k < 8; ++k) {
            float sum = 0.0f;
            #pragma unroll
            for (int j = 0; j < 8; ++j) sum += S[i * 8 + j] * V[k * 8 + j];
            r[k] = sum;
        }
        ((float4*)orow)[i * 2 + 0] = make_float4(r[0], r[1], r[2], r[3]);
        ((float4*)orow)[i * 2 + 1] = make_float4(r[4], r[5], r[6], r[7]);
    }
}

// ---------------------------------------------------------------------------
extern "C" void kernel_launch(void* const* d_in, const int* in_sizes, int n_in,
                              void* d_out, int out_size, void* d_ws, size_t ws_size,
                              hipStream_t stream) {
    const float* h_i  = (const float*)d_in[0];
    const float* npar = (const float*)d_in[1];
    const float* epar = (const float*)d_in[2];
    const float* W1   = (const float*)d_in[3];
    const float* b1   = (const float*)d_in[4];
    const float* W2   = (const float*)d_in[5];
    const float* b2   = (const float*)d_in[6];
    const float* W3   = (const float*)d_in[7];
    const float* b3   = (const float*)d_in[8];
    const float* W4   = (const float*)d_in[9];
    const float* b4   = (const float*)d_in[10];
    const int*   eidx = (const int*)d_in[11];

    const int N = in_sizes[0] / 64;
    const int E = in_sizes[11] / 2;

    float* agg = (float*)d_ws;
    hipMemsetAsync(agg, 0, (size_t)N * 16 * sizeof(float), stream);

    const int nTiles = E / TILE_E;
    int blocks = 768;
    if (blocks > nTiles) blocks = nTiles;
    k_edge<<<blocks, 256, 0, stream>>>(h_i, npar, epar, W1, b1, W2, b2,
                                       eidx, agg, N, E);
    k_node<<<(N + 255) / 256, 256, 0, stream>>>(h_i, agg, W3, b3, W4, b4,
                                                (float*)d_out, N);
}

// Round 3
// 566.908 us; speedup vs baseline: 3.7505x; 1.2029x over previous
//
#include <hip/hip_runtime.h>
#include <math.h>

#define HID1 128
#define OUT1 16
#define TILE_E 64
#define CATS 168        // W1t row stride (bf16)
#define HS   136        // hid/W2t row stride (bf16)

typedef __attribute__((ext_vector_type(8))) short bf16x8;
typedef __attribute__((ext_vector_type(4))) float f32x4;

__device__ __forceinline__ float silu(float x) {
    return x / (1.0f + __expf(-x));
}

__device__ __forceinline__ unsigned short f2bf(float x) {
    union { float f; unsigned u; } v; v.f = x;
    unsigned r = v.u + 0x7fffu + ((v.u >> 16) & 1u);   // RNE
    return (unsigned short)(r >> 16);
}

__device__ __forceinline__ unsigned pack2(float a, float b) {
    return (unsigned)f2bf(a) | ((unsigned)f2bf(b) << 16);
}

// ---------------------------------------------------------------------------
// Prep: h_i -> bf16 rows, node_params -> packed u32, edge ep-pairs -> packed u32
// ---------------------------------------------------------------------------
__global__ __launch_bounds__(256)
void k_prep(const float* __restrict__ h_i,
            const float* __restrict__ np,
            const float* __restrict__ ep,
            const int* __restrict__ eidx,
            unsigned short* __restrict__ hb,
            unsigned* __restrict__ npp,
            unsigned* __restrict__ epk,
            int N, int E)
{
    const int tid = blockIdx.x * 256 + threadIdx.x;
    const int gs = gridDim.x * 256;
    const int nh = N * 16;                     // float4 chunks of h_i
    for (int i = tid; i < nh; i += gs) {
        float4 v = ((const float4*)h_i)[i];
        uint2 u; u.x = pack2(v.x, v.y); u.y = pack2(v.z, v.w);
        ((uint2*)hb)[i] = u;
    }
    for (int i = tid; i < N; i += gs)
        npp[i] = pack2(np[2 * i], np[2 * i + 1]);
    for (int i = tid; i < E; i += gs) {
        // faithful ep quirk: ep[e][c] = edge_params[eidx_flat[2e+c]]
        epk[i] = pack2(ep[eidx[2 * i]], ep[eidx[2 * i + 1]]);
    }
}

// ---------------------------------------------------------------------------
// Kernel 1 (v3): per-edge MLP, A-fragments gathered straight to registers
// ---------------------------------------------------------------------------
__global__ __launch_bounds__(256, 2)
void k_edge_v3(const unsigned short* __restrict__ hb,   // [N][64] bf16
               const unsigned* __restrict__ npp,        // [N] (np0,np1)
               const unsigned* __restrict__ epk,        // [E] (ep0,ep1)
               const float* __restrict__ W1, const float* __restrict__ b1,
               const float* __restrict__ W2, const float* __restrict__ b2,
               const int* __restrict__ eidx,            // flat [2E]
               float* __restrict__ agg,
               int N, int E)
{
    // [ w1t 128*168 | w2t 16*136 ] us = 23680 (47360 B); hid[64][136] reuses w1t
    __shared__ __align__(16) unsigned short smem[23680];
    unsigned short* w1t = smem;
    unsigned short* w2t = smem + 128 * CATS;
    unsigned short* hid = smem;

    const int t = threadIdx.x;
    const int lane = t & 63;
    const int wv = t >> 6;
    const int wn = wv & 1;
    const int wm = wv >> 1;
    const int lr = lane & 15;
    const int lq = lane >> 4;

    // ---- stage W1^T, W2^T to LDS as bf16, then lift B-fragments to regs ----
    for (int idx = t; idx < 128 * 80; idx += 256) {
        const int col = idx & 127, kp = idx >> 7;
        const int k0 = 2 * kp;
        float f0 = (k0     < 134) ? W1[(size_t)k0       * 128 + col] : 0.0f;
        float f1 = (k0 + 1 < 134) ? W1[(size_t)(k0 + 1) * 128 + col] : 0.0f;
        *(unsigned*)&w1t[col * CATS + k0] = pack2(f0, f1);
    }
    for (int idx = t; idx < 16 * 64; idx += 256) {
        const int col = idx & 15, kp = idx >> 4;
        const int k0 = 2 * kp;
        *(unsigned*)&w2t[col * HS + k0] =
            pack2(W2[(size_t)k0 * 16 + col], W2[(size_t)(k0 + 1) * 16 + col]);
    }
    __syncthreads();

    bf16x8 bw1[4][5];
    #pragma unroll
    for (int nf = 0; nf < 4; ++nf)
        #pragma unroll
        for (int ks = 0; ks < 5; ++ks)
            bw1[nf][ks] = *(const bf16x8*)&w1t[(wn * 64 + nf * 16 + lr) * CATS + ks * 32 + lq * 8];
    bf16x8 bw2[4];
    #pragma unroll
    for (int ks = 0; ks < 4; ++ks)
        bw2[ks] = *(const bf16x8*)&w2t[lr * HS + ks * 32 + lq * 8];

    float bias1[4];
    #pragma unroll
    for (int nf = 0; nf < 4; ++nf) bias1[nf] = b1[wn * 64 + nf * 16 + lr];
    const float bias2 = b2[lr];
    __syncthreads();   // w1t region becomes hid

    const int nTiles = E >> 6;
    const uint4* hb4 = (const uint4*)hb;

    int tile = blockIdx.x;
    if (tile >= nTiles) return;

    // ---- prologue gather (ids + A-fragments for first tile) ----
    int s0, r0, s1, r1, e0g, e1g;
    uint4 aA[5], aB[5];
    {
        const int eb = tile << 6;
        e0g = eb + wm * 32 + lr;  e1g = e0g + 16;
        s0 = eidx[e0g]; r0 = eidx[E + e0g];
        s1 = eidx[e1g]; r1 = eidx[E + e1g];
        aA[0] = hb4[s0 * 8 + lq];     aA[1] = hb4[s0 * 8 + 4 + lq];
        aA[2] = hb4[r0 * 8 + lq];     aA[3] = hb4[r0 * 8 + 4 + lq];
        aB[0] = hb4[s1 * 8 + lq];     aB[1] = hb4[s1 * 8 + 4 + lq];
        aB[2] = hb4[r1 * 8 + lq];     aB[3] = hb4[r1 * 8 + 4 + lq];
        uint4 z; z.x = z.y = z.z = z.w = 0u;
        aA[4] = z; aB[4] = z;
        if (lq == 0) {
            aA[4].x = npp[s0]; aA[4].y = npp[r0]; aA[4].z = epk[e0g];
            aB[4].x = npp[s1]; aB[4].y = npp[r1]; aB[4].z = epk[e1g];
        }
    }

    for (; tile < nTiles; tile += gridDim.x) {
        const int next = tile + gridDim.x;
        const bool hn = next < nTiles;

        // prefetch next tile's edge ids (consumed mid-loop)
        int ns0 = 0, nr0 = 0, ns1 = 0, nr1 = 0, ne0 = 0, ne1 = 0;
        if (hn) {
            const int eb = next << 6;
            ne0 = eb + wm * 32 + lr;  ne1 = ne0 + 16;
            ns0 = eidx[ne0]; nr0 = eidx[E + ne0];
            ns1 = eidx[ne1]; nr1 = eidx[E + ne1];
        }

        // ---- layer 1 MFMA ----
        f32x4 acc[2][4];
        #pragma unroll
        for (int mf = 0; mf < 2; ++mf)
            #pragma unroll
            for (int nf = 0; nf < 4; ++nf)
                acc[mf][nf] = (f32x4){0.f, 0.f, 0.f, 0.f};

        #pragma unroll
        for (int ks = 0; ks < 5; ++ks) {
            const bf16x8 a0 = *(const bf16x8*)&aA[ks];
            const bf16x8 a1 = *(const bf16x8*)&aB[ks];
            #pragma unroll
            for (int nf = 0; nf < 4; ++nf) {
                acc[0][nf] = __builtin_amdgcn_mfma_f32_16x16x32_bf16(a0, bw1[nf][ks], acc[0][nf], 0, 0, 0);
                acc[1][nf] = __builtin_amdgcn_mfma_f32_16x16x32_bf16(a1, bw1[nf][ks], acc[1][nf], 0, 0, 0);
            }
        }

        // ---- bias + silu -> hid ----
        #pragma unroll
        for (int mf = 0; mf < 2; ++mf)
            #pragma unroll
            for (int nf = 0; nf < 4; ++nf) {
                const float bb = bias1[nf];
                #pragma unroll
                for (int r2 = 0; r2 < 4; ++r2) {
                    const float x = acc[mf][nf][r2] + bb;
                    hid[(wm * 32 + mf * 16 + lq * 4 + r2) * HS + wn * 64 + nf * 16 + lr] =
                        f2bf(silu(x));
                }
            }
        __syncthreads();

        // ---- prefetch next tile's A-fragments (hides under layer2+atomics) --
        if (hn) {
            s0 = ns0; r0 = nr0; s1 = ns1; r1 = nr1; e0g = ne0; e1g = ne1;
            aA[0] = hb4[s0 * 8 + lq];     aA[1] = hb4[s0 * 8 + 4 + lq];
            aA[2] = hb4[r0 * 8 + lq];     aA[3] = hb4[r0 * 8 + 4 + lq];
            aB[0] = hb4[s1 * 8 + lq];     aB[1] = hb4[s1 * 8 + 4 + lq];
            aB[2] = hb4[r1 * 8 + lq];     aB[3] = hb4[r1 * 8 + 4 + lq];
            uint4 z; z.x = z.y = z.z = z.w = 0u;
            aA[4] = z; aB[4] = z;
            if (lq == 0) {
                aA[4].x = npp[s0]; aA[4].y = npp[r0]; aA[4].z = epk[e0g];
                aB[4].x = npp[s1]; aB[4].y = npp[r1]; aB[4].z = epk[e1g];
            }
        }

        // ---- layer 2 MFMA ----
        f32x4 acc2 = (f32x4){0.f, 0.f, 0.f, 0.f};
        const unsigned short* ph = hid + (wv * 16 + lr) * HS + lq * 8;
        #pragma unroll
        for (int ks = 0; ks < 4; ++ks)
            acc2 = __builtin_amdgcn_mfma_f32_16x16x32_bf16(
                *(const bf16x8*)(ph + ks * 32), bw2[ks], acc2, 0, 0, 0);

        // ---- silu + scatter ----
        const int ebase = tile << 6;
        #pragma unroll
        for (int r2 = 0; r2 < 4; ++r2) {
            const int eg = ebase + wv * 16 + lq * 4 + r2;
            if (eg < E) {
                const int rcv = eidx[E + eg];
                atomicAdd(&agg[(size_t)rcv * 16 + lr], silu(acc2[r2] + bias2));
            }
        }
        __syncthreads();
    }
}

// ---------------------------------------------------------------------------
// Kernel 1 fallback (round-2 version, needs only agg in ws)
// ---------------------------------------------------------------------------
__global__ __launch_bounds__(256, 2)
void k_edge_v2(const float* __restrict__ h_i,
               const float* __restrict__ node_params,
               const float* __restrict__ edge_params,
               const float* __restrict__ W1, const float* __restrict__ b1,
               const float* __restrict__ W2, const float* __restrict__ b2,
               const int* __restrict__ eidx,
               float* __restrict__ agg,
               int N, int E)
{
    __shared__ unsigned short smem[23680];
    unsigned short* w1t = smem;
    unsigned short* w2t = smem + 128 * CATS;
    unsigned short* cat = smem;
    unsigned short* hid = smem + 64 * CATS;

    const int t = threadIdx.x;
    const int lane = t & 63;
    const int wv = t >> 6;
    const int wn = wv & 1;
    const int wm = wv >> 1;
    const int lr = lane & 15;
    const int lq = lane >> 4;

    for (int idx = t; idx < 128 * 80; idx += 256) {
        const int col = idx & 127, kp = idx >> 7;
        const int k0 = 2 * kp;
        float f0 = (k0     < 134) ? W1[(size_t)k0       * 128 + col] : 0.0f;
        float f1 = (k0 + 1 < 134) ? W1[(size_t)(k0 + 1) * 128 + col] : 0.0f;
        *(unsigned*)&w1t[col * CATS + k0] = pack2(f0, f1);
    }
    for (int idx = t; idx < 16 * 64; idx += 256) {
        const int col = idx & 15, kp = idx >> 4;
        const int k0 = 2 * kp;
        *(unsigned*)&w2t[col * HS + k0] =
            pack2(W2[(size_t)k0 * 16 + col], W2[(size_t)(k0 + 1) * 16 + col]);
    }
    __syncthreads();

    bf16x8 bw1[4][5];
    #pragma unroll
    for (int nf = 0; nf < 4; ++nf)
        #pragma unroll
        for (int ks = 0; ks < 5; ++ks)
            bw1[nf][ks] = *(const bf16x8*)&w1t[(wn * 64 + nf * 16 + lr) * CATS + ks * 32 + lq * 8];
    bf16x8 bw2[4];
    #pragma unroll
    for (int ks = 0; ks < 4; ++ks)
        bw2[ks] = *(const bf16x8*)&w2t[lr * HS + ks * 32 + lq * 8];

    float bias1[4];
    #pragma unroll
    for (int nf = 0; nf < 4; ++nf) bias1[nf] = b1[wn * 64 + nf * 16 + lr];
    const float bias2 = b2[lr];
    __syncthreads();

    const int el = t >> 2;
    const int p  = t & 3;

    const int nTiles = E / TILE_E;
    for (int tile = blockIdx.x; tile < nTiles; tile += gridDim.x) {
        const int ebase = tile * TILE_E;
        {
            const int eg  = ebase + el;
            const int egc = (eg < E) ? eg : (E - 1);
            const int s = eidx[egc];
            const int r = eidx[E + egc];
            const float4* hs = (const float4*)(h_i + (size_t)s * 64);
            const float4* hr = (const float4*)(h_i + (size_t)r * 64);
            unsigned short* crow = cat + el * CATS;
            #pragma unroll
            for (int m = 0; m < 8; ++m) {
                const int q = p + 4 * m;
                float4 v = (q < 16) ? hs[q] : hr[q - 16];
                uint2 u; u.x = pack2(v.x, v.y); u.y = pack2(v.z, v.w);
                *(uint2*)&crow[q * 4] = u;
            }
            if (p == 0) {
                const int i0 = eidx[2 * egc];
                const int i1 = eidx[2 * egc + 1];
                uint4 u;
                u.x = pack2(node_params[2 * s], node_params[2 * s + 1]);
                u.y = pack2(node_params[2 * r], node_params[2 * r + 1]);
                u.z = pack2(edge_params[i0], edge_params[i1]);
                u.w = 0u;
                *(uint4*)&crow[128] = u;
            } else {
                uint4 z; z.x = z.y = z.z = z.w = 0u;
                *(uint4*)&crow[136 + (p - 1) * 8] = z;
            }
        }
        __syncthreads();

        f32x4 acc[2][4];
        #pragma unroll
        for (int mf = 0; mf < 2; ++mf)
            #pragma unroll
            for (int nf = 0; nf < 4; ++nf)
                acc[mf][nf] = (f32x4){0.f, 0.f, 0.f, 0.f};

        const unsigned short* pa = cat + (wm * 32 + lr) * CATS + lq * 8;
        #pragma unroll
        for (int ks = 0; ks < 5; ++ks) {
            const bf16x8 a0 = *(const bf16x8*)(pa + ks * 32);
            const bf16x8 a1 = *(const bf16x8*)(pa + 16 * CATS + ks * 32);
            #pragma unroll
            for (int nf = 0; nf < 4; ++nf) {
                acc[0][nf] = __builtin_amdgcn_mfma_f32_16x16x32_bf16(a0, bw1[nf][ks], acc[0][nf], 0, 0, 0);
                acc[1][nf] = __builtin_amdgcn_mfma_f32_16x16x32_bf16(a1, bw1[nf][ks], acc[1][nf], 0, 0, 0);
            }
        }
        __syncthreads();

        #pragma unroll
        for (int mf = 0; mf < 2; ++mf)
            #pragma unroll
            for (int nf = 0; nf < 4; ++nf) {
                const float bb = bias1[nf];
                #pragma unroll
                for (int r2 = 0; r2 < 4; ++r2) {
                    const float x = acc[mf][nf][r2] + bb;
                    hid[(wm * 32 + mf * 16 + lq * 4 + r2) * HS + wn * 64 + nf * 16 + lr] =
                        f2bf(silu(x));
                }
            }
        __syncthreads();

        f32x4 acc2 = (f32x4){0.f, 0.f, 0.f, 0.f};
        const unsigned short* ph = hid + (wv * 16 + lr) * HS + lq * 8;
        #pragma unroll
        for (int ks = 0; ks < 4; ++ks)
            acc2 = __builtin_amdgcn_mfma_f32_16x16x32_bf16(
                *(const bf16x8*)(ph + ks * 32), bw2[ks], acc2, 0, 0, 0);

        #pragma unroll
        for (int r2 = 0; r2 < 4; ++r2) {
            const int eg2 = ebase + wv * 16 + lq * 4 + r2;
            if (eg2 < E) {
                const int rcv = eidx[E + eg2];
                const float v = silu(acc2[r2] + bias2);
                atomicAdd(&agg[(size_t)rcv * 16 + lr], v);
            }
        }
        __syncthreads();
    }
}

// ---------------------------------------------------------------------------
// Kernel 2: per-node Jacobi eigh + node MLP + softmax + V diag(lam) V^T
// ---------------------------------------------------------------------------
template <int P, int Q>
__device__ __forceinline__ void jrot(float* A, float* V) {
    const float app = A[P * 8 + P];
    const float aqq = A[Q * 8 + Q];
    const float apq = A[P * 8 + Q];
    const float absq = fabsf(apq);

    float theta = (aqq - app) / (2.0f * apq);
    float at = fabsf(theta);
    float tt = 1.0f / (at + sqrtf(at * at + 1.0f));
    tt = (theta < 0.0f) ? -tt : tt;
    float cc = __frsqrt_rn(tt * tt + 1.0f);
    float ss = tt * cc;

    const bool skip = !(absq > 1e-36f);
    const float c = skip ? 1.0f : cc;
    const float s = skip ? 0.0f : ss;

    #pragma unroll
    for (int k = 0; k < 8; ++k) {
        float ap = A[P * 8 + k], aq = A[Q * 8 + k];
        A[P * 8 + k] = c * ap - s * aq;
        A[Q * 8 + k] = s * ap + c * aq;
    }
    #pragma unroll
    for (int k = 0; k < 8; ++k) {
        float ap = A[k * 8 + P], aq = A[k * 8 + Q];
        A[k * 8 + P] = c * ap - s * aq;
        A[k * 8 + Q] = s * ap + c * aq;
    }
    #pragma unroll
    for (int k = 0; k < 8; ++k) {
        float vp = V[k * 8 + P], vq = V[k * 8 + Q];
        V[k * 8 + P] = c * vp - s * vq;
        V[k * 8 + Q] = s * vp + c * vq;
    }
}

__device__ __forceinline__ void jacobi_sweep(float* A, float* V) {
    jrot<0,1>(A,V); jrot<0,2>(A,V); jrot<0,3>(A,V); jrot<0,4>(A,V);
    jrot<0,5>(A,V); jrot<0,6>(A,V); jrot<0,7>(A,V);
    jrot<1,2>(A,V); jrot<1,3>(A,V); jrot<1,4>(A,V); jrot<1,5>(A,V);
    jrot<1,6>(A,V); jrot<1,7>(A,V);
    jrot<2,3>(A,V); jrot<2,4>(A,V); jrot<2,5>(A,V); jrot<2,6>(A,V);
    jrot<2,7>(A,V);
    jrot<3,4>(A,V); jrot<3,5>(A,V); jrot<3,6>(A,V); jrot<3,7>(A,V);
    jrot<4,5>(A,V); jrot<4,6>(A,V); jrot<4,7>(A,V);
    jrot<5,6>(A,V); jrot<5,7>(A,V);
    jrot<6,7>(A,V);
}

#define CSWAP(a, b)                                                          \
    {                                                                        \
        bool sw = eig[a] > eig[b];                                           \
        float lo = sw ? eig[b] : eig[a];                                     \
        float hi = sw ? eig[a] : eig[b];                                     \
        eig[a] = lo; eig[b] = hi;                                            \
        _Pragma("unroll")                                                    \
        for (int k = 0; k < 8; ++k) {                                        \
            float va = V[k * 8 + a], vb = V[k * 8 + b];                      \
            V[k * 8 + a] = sw ? vb : va;                                     \
            V[k * 8 + b] = sw ? va : vb;                                     \
        }                                                                    \
    }

__global__ __launch_bounds__(256)
void k_node(const float* __restrict__ h_i,
            const float* __restrict__ agg,
            const float* __restrict__ W3, const float* __restrict__ b3,
            const float* __restrict__ W4, const float* __restrict__ b4,
            float* __restrict__ out, int N)
{
    const int n = blockIdx.x * 256 + threadIdx.x;
    if (n >= N) return;

    float A[64], V[64];
    {
        const float4* src = (const float4*)(h_i + (size_t)n * 64);
        #pragma unroll
        for (int i = 0; i < 16; ++i) ((float4*)A)[i] = src[i];
    }
    #pragma unroll
    for (int i = 0; i < 64; ++i) V[i] = 0.0f;
    #pragma unroll
    for (int i = 0; i < 8; ++i) V[i * 8 + i] = 1.0f;

    #pragma unroll 1
    for (int sw = 0; sw < 5; ++sw) jacobi_sweep(A, V);

    float eig[8];
    #pragma unroll
    for (int i = 0; i < 8; ++i) eig[i] = A[i * 8 + i];

    CSWAP(0,1) CSWAP(2,3) CSWAP(4,5) CSWAP(6,7)
    CSWAP(0,2) CSWAP(1,3) CSWAP(4,6) CSWAP(5,7)
    CSWAP(1,2) CSWAP(5,6)
    CSWAP(0,4) CSWAP(1,5) CSWAP(2,6) CSWAP(3,7)
    CSWAP(2,4) CSWAP(3,5)
    CSWAP(1,2) CSWAP(3,4) CSWAP(5,6)

    float f[32];
    {
        const float4* ag = (const float4*)(agg + (size_t)n * 16);
        #pragma unroll
        for (int i = 0; i < 4; ++i) {
            float4 v = ag[i];
            f[i * 4 + 0] = v.x; f[i * 4 + 1] = v.y;
            f[i * 4 + 2] = v.z; f[i * 4 + 3] = v.w;
        }
    }
    #pragma unroll
    for (int i = 0; i < 8; ++i) f[16 + i] = eig[i];
    #pragma unroll
    for (int i = 0; i < 8; ++i) {
        float sum = 0.0f;
        #pragma unroll
        for (int j = 0; j < 8; ++j) sum += V[i * 8 + j] * V[i * 8 + j];
        f[24 + i] = sqrtf(sum);
    }

    float z[8];
    #pragma unroll
    for (int o = 0; o < 8; ++o) z[o] = b4[o];
    #pragma unroll 1
    for (int j = 0; j < 128; ++j) {
        float h = b3[j];
        #pragma unroll
        for (int k = 0; k < 32; ++k) h += f[k] * W3[k * 128 + j];
        float sv = silu(h);
        #pragma unroll
        for (int o = 0; o < 8; ++o) z[o] += sv * W4[j * 8 + o];
    }

    float m = z[0];
    #pragma unroll
    for (int o = 1; o < 8; ++o) m = fmaxf(m, z[o]);
    float lam[8], den = 0.0f;
    #pragma unroll
    for (int o = 0; o < 8; ++o) { lam[o] = __expf(z[o] - m); den += lam[o]; }
    const float inv = 1.0f / den;
    #pragma unroll
    for (int o = 0; o < 8; ++o) lam[o] *= inv;

    float S[64];
    #pragma unroll
    for (int i = 0; i < 8; ++i)
        #pragma unroll
        for (int j = 0; j < 8; ++j) S[i * 8 + j] = lam[j] * V[i * 8 + j];

    float* orow = out + (size_t)n * 64;
    #pragma unroll
    for (int i = 0; i < 8; ++i) {
        float r[8];
        #pragma unroll
        for (int k = 0; k < 8; ++k) {
            float sum = 0.0f;
            #pragma unroll
            for (int j = 0; j < 8; ++j) sum += S[i * 8 + j] * V[k * 8 + j];
            r[k] = sum;
        }
        ((float4*)orow)[i * 2 + 0] = make_float4(r[0], r[1], r[2], r[3]);
        ((float4*)orow)[i * 2 + 1] = make_float4(r[4], r[5], r[6], r[7]);
    }
}

// ---------------------------------------------------------------------------
extern "C" void kernel_launch(void* const* d_in, const int* in_sizes, int n_in,
                              void* d_out, int out_size, void* d_ws, size_t ws_size,
                              hipStream_t stream) {
    const float* h_i  = (const float*)d_in[0];
    const float* npar = (const float*)d_in[1];
    const float* epar = (const float*)d_in[2];
    const float* W1   = (const float*)d_in[3];
    const float* b1   = (const float*)d_in[4];
    const float* W2   = (const float*)d_in[5];
    const float* b2   = (const float*)d_in[6];
    const float* W3   = (const float*)d_in[7];
    const float* b3   = (const float*)d_in[8];
    const float* W4   = (const float*)d_in[9];
    const float* b4   = (const float*)d_in[10];
    const int*   eidx = (const int*)d_in[11];

    const int N = in_sizes[0] / 64;
    const int E = in_sizes[11] / 2;

    // workspace layout
    const size_t aggB = (size_t)N * 16 * sizeof(float);
    size_t off = (aggB + 255) & ~(size_t)255;
    const size_t hbOff  = off;                  off += (size_t)N * 64 * 2;
    off = (off + 255) & ~(size_t)255;
    const size_t nppOff = off;                  off += (size_t)N * 4;
    off = (off + 255) & ~(size_t)255;
    const size_t epkOff = off;                  off += (size_t)E * 4;
    const size_t need = off;

    float* agg = (float*)d_ws;
    hipMemsetAsync(agg, 0, aggB, stream);

    int blocks = E / TILE_E;
    if (blocks > 768) blocks = 768;

    if (ws_size >= need) {
        unsigned short* hb = (unsigned short*)((char*)d_ws + hbOff);
        unsigned* npp = (unsigned*)((char*)d_ws + nppOff);
        unsigned* epk = (unsigned*)((char*)d_ws + epkOff);
        k_prep<<<2048, 256, 0, stream>>>(h_i, npar, epar, eidx, hb, npp, epk, N, E);
        k_edge_v3<<<blocks, 256, 0, stream>>>(hb, npp, epk, W1, b1, W2, b2,
                                              eidx, agg, N, E);
    } else {
        k_edge_v2<<<blocks, 256, 0, stream>>>(h_i, npar, epar, W1, b1, W2, b2,
                                              eidx, agg, N, E);
    }
    k_node<<<(N + 255) / 256, 256, 0, stream>>>(h_i, agg, W3, b3, W4, b4,
                                                (float*)d_out, N);
}

// Round 4
// 461.770 us; speedup vs baseline: 4.6044x; 1.2277x over previous
//
#include <hip/hip_runtime.h>
#include <math.h>

#define HS   136        // hid row stride (bf16 units); 136*2B=272B, %16==0
#define TILE 128

typedef __attribute__((ext_vector_type(8))) short bf16x8;
typedef __attribute__((ext_vector_type(4))) float f32x4;

__device__ __forceinline__ float silu(float x) {
    return x / (1.0f + __expf(-x));
}

__device__ __forceinline__ unsigned short f2bf(float x) {
    union { float f; unsigned u; } v; v.f = x;
    unsigned r = v.u + 0x7fffu + ((v.u >> 16) & 1u);   // RNE
    return (unsigned short)(r >> 16);
}

__device__ __forceinline__ unsigned pack2(float a, float b) {
    return (unsigned)f2bf(a) | ((unsigned)f2bf(b) << 16);
}

__device__ __forceinline__ unsigned cvt_pk(float lo, float hi) {
    unsigned r;
    asm("v_cvt_pk_bf16_f32 %0, %1, %2" : "=v"(r) : "v"(lo), "v"(hi));
    return r;
}

// ---------------------------------------------------------------------------
// Prep: h_i -> bf16 rows, node_params -> packed u32, edge ep-pairs -> packed
// ---------------------------------------------------------------------------
__global__ __launch_bounds__(256)
void k_prep(const float* __restrict__ h_i,
            const float* __restrict__ np,
            const float* __restrict__ ep,
            const int* __restrict__ eidx,
            unsigned short* __restrict__ hb,
            unsigned* __restrict__ npp,
            unsigned* __restrict__ epk,
            int N, int E)
{
    const int tid = blockIdx.x * 256 + threadIdx.x;
    const int gs = gridDim.x * 256;
    const int nh = N * 16;
    for (int i = tid; i < nh; i += gs) {
        float4 v = ((const float4*)h_i)[i];
        uint2 u; u.x = pack2(v.x, v.y); u.y = pack2(v.z, v.w);
        ((uint2*)hb)[i] = u;
    }
    for (int i = tid; i < N; i += gs)
        npp[i] = pack2(np[2 * i], np[2 * i + 1]);
    for (int i = tid; i < E; i += gs)
        epk[i] = pack2(ep[eidx[2 * i]], ep[eidx[2 * i + 1]]);  // faithful quirk
}

// ---------------------------------------------------------------------------
// Kernel 1 (v4): swapped-operand MFMA, 128-edge tiles, 1 barrier/tile
//   layer1: D1[n][e] = sum_k W1[k][n] * cat[e][k]   (hid^T in D)
//   layer2: D2[e][o] = sum_k hid[e][k] * W2[k][o]
// ---------------------------------------------------------------------------
__global__ __launch_bounds__(256, 2)
void k_edge_v4(const unsigned short* __restrict__ hb,   // [N][64] bf16
               const unsigned* __restrict__ npp,        // [N]
               const unsigned* __restrict__ epk,        // [E]
               const float* __restrict__ W1, const float* __restrict__ b1,
               const float* __restrict__ W2, const float* __restrict__ b2,
               const int* __restrict__ eidx,            // flat [2E]
               float* __restrict__ agg,
               int N, int E)
{
    __shared__ __align__(16) unsigned short hidb[2][TILE * HS];  // 69632 B

    const int t = threadIdx.x;
    const int lane = t & 63;
    const int wv = t >> 6;        // wave = M-strip: n in [wv*32, wv*32+32)
    const int lr = lane & 15;
    const int lq = lane >> 4;

    // ---- weights straight to registers ----
    bf16x8 bw1[2][5];   // A-frag: lane holds W1t[n = wv*32+mf*16+lr][k=ks*32+lq*8+j]
    #pragma unroll
    for (int mf = 0; mf < 2; ++mf) {
        const int n = wv * 32 + mf * 16 + lr;
        #pragma unroll
        for (int ks = 0; ks < 5; ++ks) {
            bf16x8 w;
            #pragma unroll
            for (int j = 0; j < 8; ++j) {
                const int k = ks * 32 + lq * 8 + j;
                const float v = (k < 134) ? W1[(size_t)k * 128 + n] : 0.0f;
                w[j] = (short)f2bf(v);
            }
            bw1[mf][ks] = w;
        }
    }
    bf16x8 bw2[4];      // B-frag: lane holds W2t[o=lr][k=ks*32+lq*8+j]
    #pragma unroll
    for (int ks = 0; ks < 4; ++ks) {
        bf16x8 w;
        #pragma unroll
        for (int j = 0; j < 8; ++j) {
            const int k = ks * 32 + lq * 8 + j;
            w[j] = (short)f2bf(W2[(size_t)k * 16 + lr]);
        }
        bw2[ks] = w;
    }

    float4 b1v[2];
    #pragma unroll
    for (int mf = 0; mf < 2; ++mf)
        b1v[mf] = *(const float4*)&b1[wv * 32 + mf * 16 + lq * 4];
    const float bias2 = b2[lr];

    const uint4* hb4 = (const uint4*)hb;
    const int nT = (E + TILE - 1) / TILE;
    int p = 0;

    int tile = blockIdx.x;
    if (tile >= nT) return;

    // prologue ids
    int sid[8], rid[8];
    {
        const int eb = tile * TILE;
        #pragma unroll
        for (int ef = 0; ef < 8; ++ef) {
            int eg = eb + ef * 16 + lr;
            int egc = (eg < E) ? eg : (E - 1);
            sid[ef] = eidx[egc];
            rid[ef] = eidx[E + egc];
        }
    }

    for (; tile < nT; tile += gridDim.x) {
        const int eb = tile * TILE;
        const bool full = (eb + TILE <= E);
        const int nextT = tile + gridDim.x;

        f32x4 acc[2][8];
        #pragma unroll
        for (int mf = 0; mf < 2; ++mf)
            #pragma unroll
            for (int ef = 0; ef < 8; ++ef)
                acc[mf][ef] = (f32x4){0.f, 0.f, 0.f, 0.f};

        // ks=0 gather (sender, low half)
        uint4 cur[8], nxt[8];
        #pragma unroll
        for (int ef = 0; ef < 8; ++ef) cur[ef] = hb4[sid[ef] * 8 + lq];

        // prefetch next tile's ids while MFMAs run
        int nsid[8], nrid[8];
        if (nextT < nT) {
            const int neb = nextT * TILE;
            #pragma unroll
            for (int ef = 0; ef < 8; ++ef) {
                int eg = neb + ef * 16 + lr;
                int egc = (eg < E) ? eg : (E - 1);
                nsid[ef] = eidx[egc];
                nrid[ef] = eidx[E + egc];
            }
        }

        // ---- layer 1: 5 k-steps, load(ks+1) pipelined with mfma(ks) ----
        #pragma unroll
        for (int ks = 0; ks < 5; ++ks) {
            if (ks < 4) {
                const int kk = ks + 1;
                #pragma unroll
                for (int ef = 0; ef < 8; ++ef) {
                    if (kk < 2) {
                        nxt[ef] = hb4[sid[ef] * 8 + kk * 4 + lq];
                    } else if (kk < 4) {
                        nxt[ef] = hb4[rid[ef] * 8 + (kk - 2) * 4 + lq];
                    } else {
                        uint4 u = {0u, 0u, 0u, 0u};
                        if (lq == 0) {
                            int eg = eb + ef * 16 + lr;
                            int egc = (eg < E) ? eg : (E - 1);
                            u.x = npp[sid[ef]];
                            u.y = npp[rid[ef]];
                            u.z = epk[egc];
                        }
                        nxt[ef] = u;
                    }
                }
            }
            #pragma unroll
            for (int ef = 0; ef < 8; ++ef) {
                const bf16x8 bf = __builtin_bit_cast(bf16x8, cur[ef]);
                acc[0][ef] = __builtin_amdgcn_mfma_f32_16x16x32_bf16(bw1[0][ks], bf, acc[0][ef], 0, 0, 0);
                acc[1][ef] = __builtin_amdgcn_mfma_f32_16x16x32_bf16(bw1[1][ks], bf, acc[1][ef], 0, 0, 0);
            }
            if (ks < 4) {
                #pragma unroll
                for (int ef = 0; ef < 8; ++ef) cur[ef] = nxt[ef];
            }
        }

        // ---- bias + silu + pack -> hid[p]  (D: row=n=lq*4+r2, col=e=lr) ----
        unsigned short* hid = hidb[p];
        #pragma unroll
        for (int mf = 0; mf < 2; ++mf) {
            const float4 bb = b1v[mf];
            #pragma unroll
            for (int ef = 0; ef < 8; ++ef) {
                const float v0 = silu(acc[mf][ef][0] + bb.x);
                const float v1 = silu(acc[mf][ef][1] + bb.y);
                const float v2 = silu(acc[mf][ef][2] + bb.z);
                const float v3 = silu(acc[mf][ef][3] + bb.w);
                uint2 u; u.x = cvt_pk(v0, v1); u.y = cvt_pk(v2, v3);
                *(uint2*)&hid[(ef * 16 + lr) * HS + wv * 32 + mf * 16 + lq * 4] = u;
            }
        }
        __syncthreads();

        // carry prefetched ids forward
        if (nextT < nT) {
            #pragma unroll
            for (int ef = 0; ef < 8; ++ef) { sid[ef] = nsid[ef]; rid[ef] = nrid[ef]; }
        }

        // ---- layer 2: edges wv*32 + g*16 + (lq*4+r2), outputs o=lr ----
        #pragma unroll
        for (int g = 0; g < 2; ++g) {
            f32x4 a2 = (f32x4){0.f, 0.f, 0.f, 0.f};
            const unsigned short* ph = hid + (wv * 32 + g * 16 + lr) * HS + lq * 8;
            #pragma unroll
            for (int ks = 0; ks < 4; ++ks)
                a2 = __builtin_amdgcn_mfma_f32_16x16x32_bf16(
                    *(const bf16x8*)(ph + ks * 32), bw2[ks], a2, 0, 0, 0);

            const int e0 = eb + wv * 32 + g * 16 + lq * 4;
            if (full) {
                const int4 rcv = *(const int4*)&eidx[E + e0];
                atomicAdd(&agg[(size_t)rcv.x * 16 + lr], silu(a2[0] + bias2));
                atomicAdd(&agg[(size_t)rcv.y * 16 + lr], silu(a2[1] + bias2));
                atomicAdd(&agg[(size_t)rcv.z * 16 + lr], silu(a2[2] + bias2));
                atomicAdd(&agg[(size_t)rcv.w * 16 + lr], silu(a2[3] + bias2));
            } else {
                #pragma unroll
                for (int r2 = 0; r2 < 4; ++r2) {
                    if (e0 + r2 < E) {
                        const int rcv = eidx[E + e0 + r2];
                        atomicAdd(&agg[(size_t)rcv * 16 + lr], silu(a2[r2] + bias2));
                    }
                }
            }
        }
        p ^= 1;
    }
}

// ---------------------------------------------------------------------------
// Kernel 2: per-node Jacobi eigh (triangle-packed) + MLP + softmax + V L V^T
// ---------------------------------------------------------------------------
__host__ __device__ constexpr int tix(int i, int j) {
    return (i <= j) ? (i * 8 - (i * (i + 1)) / 2 + j)
                    : (j * 8 - (j * (j + 1)) / 2 + i);
}

template <int P, int Q>
__device__ __forceinline__ void jrot(float* T, float* V) {
    const float app = T[tix(P, P)];
    const float aqq = T[tix(Q, Q)];
    const float apq = T[tix(P, Q)];

    float theta = (aqq - app) / (2.0f * apq);
    float at = fabsf(theta);
    float tt = 1.0f / (at + sqrtf(at * at + 1.0f));
    tt = (theta < 0.0f) ? -tt : tt;
    float cc = __frsqrt_rn(tt * tt + 1.0f);
    float ss = tt * cc;

    const bool skip = !(fabsf(apq) > 1e-36f);
    const float c  = skip ? 1.0f : cc;
    const float s  = skip ? 0.0f : ss;
    const float tu = skip ? 0.0f : tt;

    // off-diagonal row/col updates (symmetric, triangle only)
    #pragma unroll
    for (int k = 0; k < 8; ++k) {
        if (k == P || k == Q) continue;
        const float akp = T[tix(k, P)], akq = T[tix(k, Q)];
        T[tix(k, P)] = c * akp - s * akq;
        T[tix(k, Q)] = s * akp + c * akq;
    }
    T[tix(P, P)] = app - tu * apq;
    T[tix(Q, Q)] = aqq + tu * apq;
    T[tix(P, Q)] = 0.0f;

    #pragma unroll
    for (int k = 0; k < 8; ++k) {
        const float vp = V[k * 8 + P], vq = V[k * 8 + Q];
        V[k * 8 + P] = c * vp - s * vq;
        V[k * 8 + Q] = s * vp + c * vq;
    }
}

__device__ __forceinline__ void jacobi_sweep(float* T, float* V) {
    jrot<0,1>(T,V); jrot<0,2>(T,V); jrot<0,3>(T,V); jrot<0,4>(T,V);
    jrot<0,5>(T,V); jrot<0,6>(T,V); jrot<0,7>(T,V);
    jrot<1,2>(T,V); jrot<1,3>(T,V); jrot<1,4>(T,V); jrot<1,5>(T,V);
    jrot<1,6>(T,V); jrot<1,7>(T,V);
    jrot<2,3>(T,V); jrot<2,4>(T,V); jrot<2,5>(T,V); jrot<2,6>(T,V);
    jrot<2,7>(T,V);
    jrot<3,4>(T,V); jrot<3,5>(T,V); jrot<3,6>(T,V); jrot<3,7>(T,V);
    jrot<4,5>(T,V); jrot<4,6>(T,V); jrot<4,7>(T,V);
    jrot<5,6>(T,V); jrot<5,7>(T,V);
    jrot<6,7>(T,V);
}

#define CSWAP(a, b)                                                          \
    {                                                                        \
        bool sw = eig[a] > eig[b];                                           \
        float lo = sw ? eig[b] : eig[a];                                     \
        float hi = sw ? eig[a] : eig[b];                                     \
        eig[a] = lo; eig[b] = hi;                                            \
        _Pragma("unroll")                                                    \
        for (int k = 0; k < 8; ++k) {                                        \
            float va = V[k * 8 + a], vb = V[k * 8 + b];                      \
            V[k * 8 + a] = sw ? vb : va;                                     \
            V[k * 8 + b] = sw ? va : vb;                                     \
        }                                                                    \
    }

__global__ __launch_bounds__(64)
void k_node(const float* __restrict__ h_i,
            const float* __restrict__ agg,
            const float* __restrict__ W3, const float* __restrict__ b3,
            const float* __restrict__ W4, const float* __restrict__ b4,
            float* __restrict__ out, int N)
{
    const int n = blockIdx.x * 64 + threadIdx.x;
    if (n >= N) return;

    float T[36], V[64];
    {
        float A[64];
        const float4* src = (const float4*)(h_i + (size_t)n * 64);
        #pragma unroll
        for (int i = 0; i < 16; ++i) ((float4*)A)[i] = src[i];
        #pragma unroll
        for (int i = 0; i < 8; ++i)
            #pragma unroll
            for (int j = 0; j < 8; ++j)
                if (i <= j) T[tix(i, j)] = A[i * 8 + j];
    }
    #pragma unroll
    for (int i = 0; i < 64; ++i) V[i] = 0.0f;
    #pragma unroll
    for (int i = 0; i < 8; ++i) V[i * 8 + i] = 1.0f;

    #pragma unroll 1
    for (int sw = 0; sw < 5; ++sw) jacobi_sweep(T, V);

    float eig[8];
    #pragma unroll
    for (int i = 0; i < 8; ++i) eig[i] = T[tix(i, i)];

    CSWAP(0,1) CSWAP(2,3) CSWAP(4,5) CSWAP(6,7)
    CSWAP(0,2) CSWAP(1,3) CSWAP(4,6) CSWAP(5,7)
    CSWAP(1,2) CSWAP(5,6)
    CSWAP(0,4) CSWAP(1,5) CSWAP(2,6) CSWAP(3,7)
    CSWAP(2,4) CSWAP(3,5)
    CSWAP(1,2) CSWAP(3,4) CSWAP(5,6)

    // feats = [agg(16) | eig(8) | 1.0 x8 (row norms of orthonormal V)]
    float f[32];
    {
        const float4* ag = (const float4*)(agg + (size_t)n * 16);
        #pragma unroll
        for (int i = 0; i < 4; ++i) {
            float4 v = ag[i];
            f[i * 4 + 0] = v.x; f[i * 4 + 1] = v.y;
            f[i * 4 + 2] = v.z; f[i * 4 + 3] = v.w;
        }
    }
    #pragma unroll
    for (int i = 0; i < 8; ++i) f[16 + i] = eig[i];
    #pragma unroll
    for (int i = 0; i < 8; ++i) f[24 + i] = 1.0f;

    float z[8];
    #pragma unroll
    for (int o = 0; o < 8; ++o) z[o] = b4[o];
    #pragma unroll 1
    for (int j = 0; j < 128; ++j) {
        float h = b3[j];
        #pragma unroll
        for (int k = 0; k < 32; ++k) h += f[k] * W3[k * 128 + j];
        const float sv = silu(h);
        #pragma unroll
        for (int o = 0; o < 8; ++o) z[o] += sv * W4[j * 8 + o];
    }

    float m = z[0];
    #pragma unroll
    for (int o = 1; o < 8; ++o) m = fmaxf(m, z[o]);
    float lam[8], den = 0.0f;
    #pragma unroll
    for (int o = 0; o < 8; ++o) { lam[o] = __expf(z[o] - m); den += lam[o]; }
    const float inv = 1.0f / den;
    #pragma unroll
    for (int o = 0; o < 8; ++o) lam[o] *= inv;

    float* orow = out + (size_t)n * 64;
    #pragma unroll
    for (int i = 0; i < 8; ++i) {
        float si[8];
        #pragma unroll
        for (int j = 0; j < 8; ++j) si[j] = lam[j] * V[i * 8 + j];
        float r[8];
        #pragma unroll
        for (int k = 0; k < 8; ++k) {
            float sum = 0.0f;
            #pragma unroll
            for (int j = 0; j < 8; ++j) sum += si[j] * V[k * 8 + j];
            r[k] = sum;
        }
        ((float4*)orow)[i * 2 + 0] = make_float4(r[0], r[1], r[2], r[3]);
        ((float4*)orow)[i * 2 + 1] = make_float4(r[4], r[5], r[6], r[7]);
    }
}

// ---------------------------------------------------------------------------
// Fallback edge kernel (round-2 style, raw fp32 inputs, needs only agg in ws)
// ---------------------------------------------------------------------------
#define CATS 168
__global__ __launch_bounds__(256, 2)
void k_edge_v2(const float* __restrict__ h_i,
               const float* __restrict__ node_params,
               const float* __restrict__ edge_params,
               const float* __restrict__ W1, const float* __restrict__ b1,
               const float* __restrict__ W2, const float* __restrict__ b2,
               const int* __restrict__ eidx,
               float* __restrict__ agg,
               int N, int E)
{
    __shared__ unsigned short smem[23680];
    unsigned short* w1t = smem;
    unsigned short* w2t = smem + 128 * CATS;
    unsigned short* cat = smem;
    unsigned short* hid = smem + 64 * CATS;

    const int t = threadIdx.x;
    const int lane = t & 63;
    const int wv = t >> 6;
    const int wn = wv & 1;
    const int wm = wv >> 1;
    const int lr = lane & 15;
    const int lq = lane >> 4;

    for (int idx = t; idx < 128 * 80; idx += 256) {
        const int col = idx & 127, kp = idx >> 7;
        const int k0 = 2 * kp;
        float f0 = (k0     < 134) ? W1[(size_t)k0       * 128 + col] : 0.0f;
        float f1 = (k0 + 1 < 134) ? W1[(size_t)(k0 + 1) * 128 + col] : 0.0f;
        *(unsigned*)&w1t[col * CATS + k0] = pack2(f0, f1);
    }
    for (int idx = t; idx < 16 * 64; idx += 256) {
        const int col = idx & 15, kp = idx >> 4;
        const int k0 = 2 * kp;
        *(unsigned*)&w2t[col * HS + k0] =
            pack2(W2[(size_t)k0 * 16 + col], W2[(size_t)(k0 + 1) * 16 + col]);
    }
    __syncthreads();

    bf16x8 bw1[4][5];
    #pragma unroll
    for (int nf = 0; nf < 4; ++nf)
        #pragma unroll
        for (int ks = 0; ks < 5; ++ks)
            bw1[nf][ks] = *(const bf16x8*)&w1t[(wn * 64 + nf * 16 + lr) * CATS + ks * 32 + lq * 8];
    bf16x8 bw2[4];
    #pragma unroll
    for (int ks = 0; ks < 4; ++ks)
        bw2[ks] = *(const bf16x8*)&w2t[lr * HS + ks * 32 + lq * 8];

    float bias1[4];
    #pragma unroll
    for (int nf = 0; nf < 4; ++nf) bias1[nf] = b1[wn * 64 + nf * 16 + lr];
    const float bias2 = b2[lr];
    __syncthreads();

    const int el = t >> 2;
    const int p  = t & 3;

    const int nTiles = E / 64;
    for (int tile = blockIdx.x; tile < nTiles; tile += gridDim.x) {
        const int ebase = tile * 64;
        {
            const int eg  = ebase + el;
            const int egc = (eg < E) ? eg : (E - 1);
            const int s = eidx[egc];
            const int r = eidx[E + egc];
            const float4* hs = (const float4*)(h_i + (size_t)s * 64);
            const float4* hr = (const float4*)(h_i + (size_t)r * 64);
            unsigned short* crow = cat + el * CATS;
            #pragma unroll
            for (int m = 0; m < 8; ++m) {
                const int q = p + 4 * m;
                float4 v = (q < 16) ? hs[q] : hr[q - 16];
                uint2 u; u.x = pack2(v.x, v.y); u.y = pack2(v.z, v.w);
                *(uint2*)&crow[q * 4] = u;
            }
            if (p == 0) {
                const int i0 = eidx[2 * egc];
                const int i1 = eidx[2 * egc + 1];
                uint4 u;
                u.x = pack2(node_params[2 * s], node_params[2 * s + 1]);
                u.y = pack2(node_params[2 * r], node_params[2 * r + 1]);
                u.z = pack2(edge_params[i0], edge_params[i1]);
                u.w = 0u;
                *(uint4*)&crow[128] = u;
            } else {
                uint4 z; z.x = z.y = z.z = z.w = 0u;
                *(uint4*)&crow[136 + (p - 1) * 8] = z;
            }
        }
        __syncthreads();

        f32x4 acc[2][4];
        #pragma unroll
        for (int mf = 0; mf < 2; ++mf)
            #pragma unroll
            for (int nf = 0; nf < 4; ++nf)
                acc[mf][nf] = (f32x4){0.f, 0.f, 0.f, 0.f};

        const unsigned short* pa = cat + (wm * 32 + lr) * CATS + lq * 8;
        #pragma unroll
        for (int ks = 0; ks < 5; ++ks) {
            const bf16x8 a0 = *(const bf16x8*)(pa + ks * 32);
            const bf16x8 a1 = *(const bf16x8*)(pa + 16 * CATS + ks * 32);
            #pragma unroll
            for (int nf = 0; nf < 4; ++nf) {
                acc[0][nf] = __builtin_amdgcn_mfma_f32_16x16x32_bf16(a0, bw1[nf][ks], acc[0][nf], 0, 0, 0);
                acc[1][nf] = __builtin_amdgcn_mfma_f32_16x16x32_bf16(a1, bw1[nf][ks], acc[1][nf], 0, 0, 0);
            }
        }
        __syncthreads();

        #pragma unroll
        for (int mf = 0; mf < 2; ++mf)
            #pragma unroll
            for (int nf = 0; nf < 4; ++nf) {
                const float bb = bias1[nf];
                #pragma unroll
                for (int r2 = 0; r2 < 4; ++r2) {
                    const float x = acc[mf][nf][r2] + bb;
                    hid[(wm * 32 + mf * 16 + lq * 4 + r2) * HS + wn * 64 + nf * 16 + lr] =
                        f2bf(silu(x));
                }
            }
        __syncthreads();

        f32x4 acc2 = (f32x4){0.f, 0.f, 0.f, 0.f};
        const unsigned short* ph = hid + (wv * 16 + lr) * HS + lq * 8;
        #pragma unroll
        for (int ks = 0; ks < 4; ++ks)
            acc2 = __builtin_amdgcn_mfma_f32_16x16x32_bf16(
                *(const bf16x8*)(ph + ks * 32), bw2[ks], acc2, 0, 0, 0);

        #pragma unroll
        for (int r2 = 0; r2 < 4; ++r2) {
            const int eg2 = ebase + wv * 16 + lq * 4 + r2;
            if (eg2 < E) {
                const int rcv = eidx[E + eg2];
                const float v = silu(acc2[r2] + bias2);
                atomicAdd(&agg[(size_t)rcv * 16 + lr], v);
            }
        }
        __syncthreads();
    }
}

// ---------------------------------------------------------------------------
extern "C" void kernel_launch(void* const* d_in, const int* in_sizes, int n_in,
                              void* d_out, int out_size, void* d_ws, size_t ws_size,
                              hipStream_t stream) {
    const float* h_i  = (const float*)d_in[0];
    const float* npar = (const float*)d_in[1];
    const float* epar = (const float*)d_in[2];
    const float* W1   = (const float*)d_in[3];
    const float* b1   = (const float*)d_in[4];
    const float* W2   = (const float*)d_in[5];
    const float* b2   = (const float*)d_in[6];
    const float* W3   = (const float*)d_in[7];
    const float* b3   = (const float*)d_in[8];
    const float* W4   = (const float*)d_in[9];
    const float* b4   = (const float*)d_in[10];
    const int*   eidx = (const int*)d_in[11];

    const int N = in_sizes[0] / 64;
    const int E = in_sizes[11] / 2;

    // workspace layout: agg | hb | npp | epk
    const size_t aggB = (size_t)N * 16 * sizeof(float);
    size_t off = (aggB + 255) & ~(size_t)255;
    const size_t hbOff  = off;                  off += (size_t)N * 64 * 2;
    off = (off + 255) & ~(size_t)255;
    const size_t nppOff = off;                  off += (size_t)N * 4;
    off = (off + 255) & ~(size_t)255;
    const size_t epkOff = off;                  off += (size_t)E * 4;
    const size_t need = off;

    float* agg = (float*)d_ws;
    hipMemsetAsync(agg, 0, aggB, stream);

    if (ws_size >= need) {
        unsigned short* hb = (unsigned short*)((char*)d_ws + hbOff);
        unsigned* npp = (unsigned*)((char*)d_ws + nppOff);
        unsigned* epk = (unsigned*)((char*)d_ws + epkOff);
        k_prep<<<2048, 256, 0, stream>>>(h_i, npar, epar, eidx, hb, npp, epk, N, E);

        int blocks = (E + TILE - 1) / TILE;
        if (blocks > 512) blocks = 512;
        k_edge_v4<<<blocks, 256, 0, stream>>>(hb, npp, epk, W1, b1, W2, b2,
                                              eidx, agg, N, E);
    } else {
        int blocks = E / 64;
        if (blocks > 768) blocks = 768;
        k_edge_v2<<<blocks, 256, 0, stream>>>(h_i, npar, epar, W1, b1, W2, b2,
                                              eidx, agg, N, E);
    }
    k_node<<<(N + 63) / 64, 64, 0, stream>>>(h_i, agg, W3, b3, W4, b4,
                                             (float*)d_out, N);
}

// Round 5
// 323.725 us; speedup vs baseline: 6.5679x; 1.4264x over previous
//
#include <hip/hip_runtime.h>
#include <math.h>

typedef __attribute__((ext_vector_type(8))) short bf16x8;
typedef __attribute__((ext_vector_type(4))) float f32x4;
typedef _Float16 half2v __attribute__((ext_vector_type(2)));

__device__ __forceinline__ float silu(float x) {
    return x / (1.0f + __expf(-x));
}

__device__ __forceinline__ unsigned short f2bf(float x) {
    union { float f; unsigned u; } v; v.f = x;
    unsigned r = v.u + 0x7fffu + ((v.u >> 16) & 1u);   // RNE
    return (unsigned short)(r >> 16);
}

__device__ __forceinline__ unsigned pack2(float a, float b) {   // 2x bf16
    return (unsigned)f2bf(a) | ((unsigned)f2bf(b) << 16);
}

__device__ __forceinline__ unsigned pack2h(float a, float b) {  // 2x fp16
    half2v h; h[0] = (_Float16)a; h[1] = (_Float16)b;
    return __builtin_bit_cast(unsigned, h);
}

__device__ __forceinline__ unsigned cvt_pk(float lo, float hi) { // 2x bf16 RNE
    unsigned r;
    asm("v_cvt_pk_bf16_f32 %0, %1, %2" : "=v"(r) : "v"(lo), "v"(hi));
    return r;
}

// ---------------------------------------------------------------------------
// Prep: np -> packed bf16 pairs; edge ep-pairs (faithful quirk) -> packed fp16
// ---------------------------------------------------------------------------
__global__ __launch_bounds__(256)
void k_prep(const float* __restrict__ np,
            const float* __restrict__ ep,
            const int* __restrict__ eidx,
            unsigned* __restrict__ npp,
            unsigned* __restrict__ epk,
            int N, int E)
{
    const int tid = blockIdx.x * 256 + threadIdx.x;
    const int gs = gridDim.x * 256;
    for (int i = tid; i < N; i += gs)
        npp[i] = pack2(np[2 * i], np[2 * i + 1]);
    for (int i = tid; i < E; i += gs)
        epk[i] = pack2h(ep[eidx[2 * i]], ep[eidx[2 * i + 1]]);
}

// ---------------------------------------------------------------------------
// k_pre: SAB[n][256] fp16 = [ SA | SB ]
//   SA[n] = h[n]@W1[0:64]   + np[n]@W1[128:130] + b1
//   SB[n] = h[n]@W1[64:128] + np[n]@W1[130:132]
// swapped-operand MFMA: D[c][node], 16 nodes x 256 cols per block (4 waves)
// ---------------------------------------------------------------------------
__global__ __launch_bounds__(256)
void k_pre(const float* __restrict__ h_i,
           const unsigned* __restrict__ npp,
           const float* __restrict__ W1, const float* __restrict__ b1,
           unsigned short* __restrict__ SAB, int N)
{
    const int t = threadIdx.x;
    const int lane = t & 63;
    const int wv = t >> 6;        // col strip: c in [wv*64, wv*64+64)
    const int lr = lane & 15;
    const int lq = lane >> 4;

    // A-frags (Wc^T): lane holds Wc[k=ks*32+lq*8+j][c=wv*64+mf*16+lr]
    bf16x8 aw[4][3];
    #pragma unroll
    for (int mf = 0; mf < 4; ++mf) {
        const int c = wv * 64 + mf * 16 + lr;
        const bool isA = c < 128;
        const int col = c & 127;
        #pragma unroll
        for (int ks = 0; ks < 3; ++ks) {
            bf16x8 w;
            #pragma unroll
            for (int j = 0; j < 8; ++j) {
                const int kl = lq * 8 + j;
                float v = 0.0f;
                if (ks < 2) {
                    const int kk = ks * 32 + kl;
                    v = W1[(size_t)(isA ? kk : 64 + kk) * 128 + col];
                } else if (kl < 2) {
                    v = W1[(size_t)((isA ? 128 : 130) + kl) * 128 + col];
                }
                w[j] = (short)f2bf(v);
            }
            aw[mf][ks] = w;
        }
    }
    float4 b1v[4];
    #pragma unroll
    for (int mf = 0; mf < 4; ++mf) {
        if (wv < 2) b1v[mf] = *(const float4*)&b1[wv * 64 + mf * 16 + lq * 4];
        else        b1v[mf] = make_float4(0.f, 0.f, 0.f, 0.f);
    }

    const int nTiles = (N + 15) / 16;
    for (int tile = blockIdx.x; tile < nTiles; tile += gridDim.x) {
        const int n  = tile * 16 + lr;
        const int nc = (n < N) ? n : (N - 1);

        // B-frags: X[node=lr][k]
        const float* hr = h_i + (size_t)nc * 64;
        bf16x8 B0, B1, B2;
        {
            float4 a0 = *(const float4*)&hr[lq * 8];
            float4 a1 = *(const float4*)&hr[lq * 8 + 4];
            float4 a2 = *(const float4*)&hr[32 + lq * 8];
            float4 a3 = *(const float4*)&hr[32 + lq * 8 + 4];
            unsigned u[4];
            u[0] = pack2(a0.x, a0.y); u[1] = pack2(a0.z, a0.w);
            u[2] = pack2(a1.x, a1.y); u[3] = pack2(a1.z, a1.w);
            B0 = __builtin_bit_cast(bf16x8, *(uint4*)u);
            u[0] = pack2(a2.x, a2.y); u[1] = pack2(a2.z, a2.w);
            u[2] = pack2(a3.x, a3.y); u[3] = pack2(a3.z, a3.w);
            B1 = __builtin_bit_cast(bf16x8, *(uint4*)u);
            unsigned z[4] = {0u, 0u, 0u, 0u};
            if (lq == 0) z[0] = npp[nc];
            B2 = __builtin_bit_cast(bf16x8, *(uint4*)z);
        }

        f32x4 acc[4];
        #pragma unroll
        for (int mf = 0; mf < 4; ++mf) {
            acc[mf] = (f32x4){0.f, 0.f, 0.f, 0.f};
            acc[mf] = __builtin_amdgcn_mfma_f32_16x16x32_bf16(aw[mf][0], B0, acc[mf], 0, 0, 0);
            acc[mf] = __builtin_amdgcn_mfma_f32_16x16x32_bf16(aw[mf][1], B1, acc[mf], 0, 0, 0);
            acc[mf] = __builtin_amdgcn_mfma_f32_16x16x32_bf16(aw[mf][2], B2, acc[mf], 0, 0, 0);
        }

        if (n < N) {
            unsigned short* row = SAB + (size_t)n * 256;
            #pragma unroll
            for (int mf = 0; mf < 4; ++mf) {
                uint2 u;
                u.x = pack2h(acc[mf][0] + b1v[mf].x, acc[mf][1] + b1v[mf].y);
                u.y = pack2h(acc[mf][2] + b1v[mf].z, acc[mf][3] + b1v[mf].w);
                *(uint2*)&row[wv * 64 + mf * 16 + lq * 4] = u;
            }
        }
    }
}

// ---------------------------------------------------------------------------
// k_edge_v5: barrier-free, LDS-free. Each wave owns 16 edges per group.
//   pre = SA[s] + SB[r] + ep0*W1[132] + ep1*W1[133]  (packed fp16)
//   hidden = silu(pre) -> bf16 A-frag (in regs) -> layer2 MFMA -> scatter
// ---------------------------------------------------------------------------
__global__ __launch_bounds__(256, 3)
void k_edge_v5(const unsigned short* __restrict__ SAB,  // [N][256] fp16
               const unsigned* __restrict__ epk,        // [E] fp16 pair
               const int* __restrict__ eidx,            // flat [2E]
               const float* __restrict__ W1,
               const float* __restrict__ W2, const float* __restrict__ b2,
               float* __restrict__ agg,
               int N, int E)
{
    const int t = threadIdx.x;
    const int lane = t & 63;
    const int wv = t >> 6;
    const int lr = lane & 15;
    const int lq = lane >> 4;

    // per-lane fp16-pair slices of W1 rows 132/133: dims d = ks*32+lq*8+2c(,+1)
    half2v wA[4][4], wB[4][4];
    #pragma unroll
    for (int ks = 0; ks < 4; ++ks)
        #pragma unroll
        for (int c = 0; c < 4; ++c) {
            const int d = ks * 32 + lq * 8 + 2 * c;
            half2v a; a[0] = (_Float16)W1[132 * 128 + d]; a[1] = (_Float16)W1[132 * 128 + d + 1];
            half2v b; b[0] = (_Float16)W1[133 * 128 + d]; b[1] = (_Float16)W1[133 * 128 + d + 1];
            wA[ks][c] = a; wB[ks][c] = b;
        }

    // layer-2 B-frags
    bf16x8 bw2[4];
    #pragma unroll
    for (int ks = 0; ks < 4; ++ks) {
        bf16x8 w;
        #pragma unroll
        for (int j = 0; j < 8; ++j) {
            const int k = ks * 32 + lq * 8 + j;
            w[j] = (short)f2bf(W2[(size_t)k * 16 + lr]);
        }
        bw2[ks] = w;
    }
    const float bias2 = b2[lr];

    const uint4* S4 = (const uint4*)SAB;   // 32 uint4 per node row
    const int nG = (E + 15) / 16;
    const int gstride = gridDim.x * 4;
    int g = blockIdx.x * 4 + wv;
    if (g >= nG) return;

    // ---- prologue: ids + SAB slices for first group ----
    int s0, r0; unsigned ep0; int rc0[4];
    uint4 A0[4], B0[4];
    {
        const int eb = g * 16;
        const int e = eb + lr; const int ec = (e < E) ? e : (E - 1);
        s0 = eidx[ec]; r0 = eidx[E + ec]; ep0 = epk[ec];
        if (eb + 16 <= E) {
            const int4 rv = *(const int4*)&eidx[E + eb + lq * 4];
            rc0[0] = rv.x; rc0[1] = rv.y; rc0[2] = rv.z; rc0[3] = rv.w;
        } else {
            #pragma unroll
            for (int r2 = 0; r2 < 4; ++r2) {
                int e4 = eb + lq * 4 + r2;
                rc0[r2] = eidx[E + ((e4 < E) ? e4 : (E - 1))];
            }
        }
        const uint4* pa = S4 + (size_t)s0 * 32;
        const uint4* pb = S4 + (size_t)r0 * 32 + 16;
        #pragma unroll
        for (int ks = 0; ks < 4; ++ks) { A0[ks] = pa[ks * 4 + lq]; B0[ks] = pb[ks * 4 + lq]; }
    }

    for (; g < nG; g += gstride) {
        const int gn = g + gstride;
        const bool hn = gn < nG;

        // prefetch next group's ids
        int s1 = 0, r1 = 0; unsigned ep1 = 0; int rc1[4] = {0, 0, 0, 0};
        if (hn) {
            const int eb = gn * 16;
            const int e = eb + lr; const int ec = (e < E) ? e : (E - 1);
            s1 = eidx[ec]; r1 = eidx[E + ec]; ep1 = epk[ec];
            if (eb + 16 <= E) {
                const int4 rv = *(const int4*)&eidx[E + eb + lq * 4];
                rc1[0] = rv.x; rc1[1] = rv.y; rc1[2] = rv.z; rc1[3] = rv.w;
            } else {
                #pragma unroll
                for (int r2 = 0; r2 < 4; ++r2) {
                    int e4 = eb + lq * 4 + r2;
                    rc1[r2] = eidx[E + ((e4 < E) ? e4 : (E - 1))];
                }
            }
        }

        // ---- fused add + ep-fma (packed fp16) + silu -> bf16 A-frags ----
        const unsigned elo = (ep0 & 0xffffu) | (ep0 << 16);
        const unsigned ehi = (ep0 >> 16) | (ep0 & 0xffff0000u);
        const half2v e0 = __builtin_bit_cast(half2v, elo);
        const half2v e1 = __builtin_bit_cast(half2v, ehi);

        bf16x8 af[4];
        #pragma unroll
        for (int ks = 0; ks < 4; ++ks) {
            unsigned w[4];
            const unsigned* ua = (const unsigned*)&A0[ks];
            const unsigned* ub = (const unsigned*)&B0[ks];
            #pragma unroll
            for (int c = 0; c < 4; ++c) {
                half2v v = __builtin_bit_cast(half2v, ua[c])
                         + __builtin_bit_cast(half2v, ub[c]);
                v = wA[ks][c] * e0 + v;
                v = wB[ks][c] * e1 + v;
                const float x0 = (float)v[0];
                const float x1 = (float)v[1];
                w[c] = cvt_pk(silu(x0), silu(x1));
            }
            af[ks] = __builtin_bit_cast(bf16x8, *(uint4*)w);
        }

        // issue next group's SAB gathers (hide under MFMA+atomics+next silu)
        uint4 A1[4], B1[4];
        if (hn) {
            const uint4* pa = S4 + (size_t)s1 * 32;
            const uint4* pb = S4 + (size_t)r1 * 32 + 16;
            #pragma unroll
            for (int ks = 0; ks < 4; ++ks) { A1[ks] = pa[ks * 4 + lq]; B1[ks] = pb[ks * 4 + lq]; }
        }

        // ---- layer 2 MFMA ----
        f32x4 acc = (f32x4){0.f, 0.f, 0.f, 0.f};
        #pragma unroll
        for (int ks = 0; ks < 4; ++ks)
            acc = __builtin_amdgcn_mfma_f32_16x16x32_bf16(af[ks], bw2[ks], acc, 0, 0, 0);

        // ---- silu + scatter (D: row=edge=lq*4+r2, col=out=lr) ----
        const int eb = g * 16;
        if (eb + 16 <= E) {
            #pragma unroll
            for (int r2 = 0; r2 < 4; ++r2)
                atomicAdd(&agg[(size_t)rc0[r2] * 16 + lr], silu(acc[r2] + bias2));
        } else {
            #pragma unroll
            for (int r2 = 0; r2 < 4; ++r2)
                if (eb + lq * 4 + r2 < E)
                    atomicAdd(&agg[(size_t)rc0[r2] * 16 + lr], silu(acc[r2] + bias2));
        }

        // roll pipeline state
        if (hn) {
            s0 = s1; r0 = r1; ep0 = ep1;
            #pragma unroll
            for (int r2 = 0; r2 < 4; ++r2) rc0[r2] = rc1[r2];
            #pragma unroll
            for (int ks = 0; ks < 4; ++ks) { A0[ks] = A1[ks]; B0[ks] = B1[ks]; }
        }
    }
}

// ---------------------------------------------------------------------------
// Kernel 2: per-node Jacobi eigh (triangle-packed) + MLP + softmax + V L V^T
// (unchanged from round 4 — known good)
// ---------------------------------------------------------------------------
__host__ __device__ constexpr int tix(int i, int j) {
    return (i <= j) ? (i * 8 - (i * (i + 1)) / 2 + j)
                    : (j * 8 - (j * (j + 1)) / 2 + i);
}

template <int P, int Q>
__device__ __forceinline__ void jrot(float* T, float* V) {
    const float app = T[tix(P, P)];
    const float aqq = T[tix(Q, Q)];
    const float apq = T[tix(P, Q)];

    float theta = (aqq - app) / (2.0f * apq);
    float at = fabsf(theta);
    float tt = 1.0f / (at + sqrtf(at * at + 1.0f));
    tt = (theta < 0.0f) ? -tt : tt;
    float cc = __frsqrt_rn(tt * tt + 1.0f);
    float ss = tt * cc;

    const bool skip = !(fabsf(apq) > 1e-36f);
    const float c  = skip ? 1.0f : cc;
    const float s  = skip ? 0.0f : ss;
    const float tu = skip ? 0.0f : tt;

    #pragma unroll
    for (int k = 0; k < 8; ++k) {
        if (k == P || k == Q) continue;
        const float akp = T[tix(k, P)], akq = T[tix(k, Q)];
        T[tix(k, P)] = c * akp - s * akq;
        T[tix(k, Q)] = s * akp + c * akq;
    }
    T[tix(P, P)] = app - tu * apq;
    T[tix(Q, Q)] = aqq + tu * apq;
    T[tix(P, Q)] = 0.0f;

    #pragma unroll
    for (int k = 0; k < 8; ++k) {
        const float vp = V[k * 8 + P], vq = V[k * 8 + Q];
        V[k * 8 + P] = c * vp - s * vq;
        V[k * 8 + Q] = s * vp + c * vq;
    }
}

__device__ __forceinline__ void jacobi_sweep(float* T, float* V) {
    jrot<0,1>(T,V); jrot<0,2>(T,V); jrot<0,3>(T,V); jrot<0,4>(T,V);
    jrot<0,5>(T,V); jrot<0,6>(T,V); jrot<0,7>(T,V);
    jrot<1,2>(T,V); jrot<1,3>(T,V); jrot<1,4>(T,V); jrot<1,5>(T,V);
    jrot<1,6>(T,V); jrot<1,7>(T,V);
    jrot<2,3>(T,V); jrot<2,4>(T,V); jrot<2,5>(T,V); jrot<2,6>(T,V);
    jrot<2,7>(T,V);
    jrot<3,4>(T,V); jrot<3,5>(T,V); jrot<3,6>(T,V); jrot<3,7>(T,V);
    jrot<4,5>(T,V); jrot<4,6>(T,V); jrot<4,7>(T,V);
    jrot<5,6>(T,V); jrot<5,7>(T,V);
    jrot<6,7>(T,V);
}

#define CSWAP(a, b)                                                          \
    {                                                                        \
        bool sw = eig[a] > eig[b];                                           \
        float lo = sw ? eig[b] : eig[a];                                     \
        float hi = sw ? eig[a] : eig[b];                                     \
        eig[a] = lo; eig[b] = hi;                                            \
        _Pragma("unroll")                                                    \
        for (int k = 0; k < 8; ++k) {                                        \
            float va = V[k * 8 + a], vb = V[k * 8 + b];                      \
            V[k * 8 + a] = sw ? vb : va;                                     \
            V[k * 8 + b] = sw ? va : vb;                                     \
        }                                                                    \
    }

__global__ __launch_bounds__(64)
void k_node(const float* __restrict__ h_i,
            const float* __restrict__ agg,
            const float* __restrict__ W3, const float* __restrict__ b3,
            const float* __restrict__ W4, const float* __restrict__ b4,
            float* __restrict__ out, int N)
{
    const int n = blockIdx.x * 64 + threadIdx.x;
    if (n >= N) return;

    float T[36], V[64];
    {
        float A[64];
        const float4* src = (const float4*)(h_i + (size_t)n * 64);
        #pragma unroll
        for (int i = 0; i < 16; ++i) ((float4*)A)[i] = src[i];
        #pragma unroll
        for (int i = 0; i < 8; ++i)
            #pragma unroll
            for (int j = 0; j < 8; ++j)
                if (i <= j) T[tix(i, j)] = A[i * 8 + j];
    }
    #pragma unroll
    for (int i = 0; i < 64; ++i) V[i] = 0.0f;
    #pragma unroll
    for (int i = 0; i < 8; ++i) V[i * 8 + i] = 1.0f;

    #pragma unroll 1
    for (int sw = 0; sw < 5; ++sw) jacobi_sweep(T, V);

    float eig[8];
    #pragma unroll
    for (int i = 0; i < 8; ++i) eig[i] = T[tix(i, i)];

    CSWAP(0,1) CSWAP(2,3) CSWAP(4,5) CSWAP(6,7)
    CSWAP(0,2) CSWAP(1,3) CSWAP(4,6) CSWAP(5,7)
    CSWAP(1,2) CSWAP(5,6)
    CSWAP(0,4) CSWAP(1,5) CSWAP(2,6) CSWAP(3,7)
    CSWAP(2,4) CSWAP(3,5)
    CSWAP(1,2) CSWAP(3,4) CSWAP(5,6)

    float f[32];
    {
        const float4* ag = (const float4*)(agg + (size_t)n * 16);
        #pragma unroll
        for (int i = 0; i < 4; ++i) {
            float4 v = ag[i];
            f[i * 4 + 0] = v.x; f[i * 4 + 1] = v.y;
            f[i * 4 + 2] = v.z; f[i * 4 + 3] = v.w;
        }
    }
    #pragma unroll
    for (int i = 0; i < 8; ++i) f[16 + i] = eig[i];
    #pragma unroll
    for (int i = 0; i < 8; ++i) f[24 + i] = 1.0f;

    float z[8];
    #pragma unroll
    for (int o = 0; o < 8; ++o) z[o] = b4[o];
    #pragma unroll 1
    for (int j = 0; j < 128; ++j) {
        float h = b3[j];
        #pragma unroll
        for (int k = 0; k < 32; ++k) h += f[k] * W3[k * 128 + j];
        const float sv = silu(h);
        #pragma unroll
        for (int o = 0; o < 8; ++o) z[o] += sv * W4[j * 8 + o];
    }

    float m = z[0];
    #pragma unroll
    for (int o = 1; o < 8; ++o) m = fmaxf(m, z[o]);
    float lam[8], den = 0.0f;
    #pragma unroll
    for (int o = 0; o < 8; ++o) { lam[o] = __expf(z[o] - m); den += lam[o]; }
    const float inv = 1.0f / den;
    #pragma unroll
    for (int o = 0; o < 8; ++o) lam[o] *= inv;

    float* orow = out + (size_t)n * 64;
    #pragma unroll
    for (int i = 0; i < 8; ++i) {
        float si[8];
        #pragma unroll
        for (int j = 0; j < 8; ++j) si[j] = lam[j] * V[i * 8 + j];
        float r[8];
        #pragma unroll
        for (int k = 0; k < 8; ++k) {
            float sum = 0.0f;
            #pragma unroll
            for (int j = 0; j < 8; ++j) sum += si[j] * V[k * 8 + j];
            r[k] = sum;
        }
        ((float4*)orow)[i * 2 + 0] = make_float4(r[0], r[1], r[2], r[3]);
        ((float4*)orow)[i * 2 + 1] = make_float4(r[4], r[5], r[6], r[7]);
    }
}

// ---------------------------------------------------------------------------
// Fallback edge kernel (round-2 style, raw fp32 inputs, needs only agg in ws)
// ---------------------------------------------------------------------------
#define CATS 168
#define HS   136
__global__ __launch_bounds__(256, 2)
void k_edge_v2(const float* __restrict__ h_i,
               const float* __restrict__ node_params,
               const float* __restrict__ edge_params,
               const float* __restrict__ W1, const float* __restrict__ b1,
               const float* __restrict__ W2, const float* __restrict__ b2,
               const int* __restrict__ eidx,
               float* __restrict__ agg,
               int N, int E)
{
    __shared__ unsigned short smem[23680];
    unsigned short* w1t = smem;
    unsigned short* w2t = smem + 128 * CATS;
    unsigned short* cat = smem;
    unsigned short* hid = smem + 64 * CATS;

    const int t = threadIdx.x;
    const int lane = t & 63;
    const int wv = t >> 6;
    const int wn = wv & 1;
    const int wm = wv >> 1;
    const int lr = lane & 15;
    const int lq = lane >> 4;

    for (int idx = t; idx < 128 * 80; idx += 256) {
        const int col = idx & 127, kp = idx >> 7;
        const int k0 = 2 * kp;
        float f0 = (k0     < 134) ? W1[(size_t)k0       * 128 + col] : 0.0f;
        float f1 = (k0 + 1 < 134) ? W1[(size_t)(k0 + 1) * 128 + col] : 0.0f;
        *(unsigned*)&w1t[col * CATS + k0] = pack2(f0, f1);
    }
    for (int idx = t; idx < 16 * 64; idx += 256) {
        const int col = idx & 15, kp = idx >> 4;
        const int k0 = 2 * kp;
        *(unsigned*)&w2t[col * HS + k0] =
            pack2(W2[(size_t)k0 * 16 + col], W2[(size_t)(k0 + 1) * 16 + col]);
    }
    __syncthreads();

    bf16x8 bw1[4][5];
    #pragma unroll
    for (int nf = 0; nf < 4; ++nf)
        #pragma unroll
        for (int ks = 0; ks < 5; ++ks)
            bw1[nf][ks] = *(const bf16x8*)&w1t[(wn * 64 + nf * 16 + lr) * CATS + ks * 32 + lq * 8];
    bf16x8 bw2[4];
    #pragma unroll
    for (int ks = 0; ks < 4; ++ks)
        bw2[ks] = *(const bf16x8*)&w2t[lr * HS + ks * 32 + lq * 8];

    float bias1[4];
    #pragma unroll
    for (int nf = 0; nf < 4; ++nf) bias1[nf] = b1[wn * 64 + nf * 16 + lr];
    const float bias2 = b2[lr];
    __syncthreads();

    const int el = t >> 2;
    const int p  = t & 3;

    const int nTiles = E / 64;
    for (int tile = blockIdx.x; tile < nTiles; tile += gridDim.x) {
        const int ebase = tile * 64;
        {
            const int eg  = ebase + el;
            const int egc = (eg < E) ? eg : (E - 1);
            const int s = eidx[egc];
            const int r = eidx[E + egc];
            const float4* hs = (const float4*)(h_i + (size_t)s * 64);
            const float4* hr = (const float4*)(h_i + (size_t)r * 64);
            unsigned short* crow = cat + el * CATS;
            #pragma unroll
            for (int m = 0; m < 8; ++m) {
                const int q = p + 4 * m;
                float4 v = (q < 16) ? hs[q] : hr[q - 16];
                uint2 u; u.x = pack2(v.x, v.y); u.y = pack2(v.z, v.w);
                *(uint2*)&crow[q * 4] = u;
            }
            if (p == 0) {
                const int i0 = eidx[2 * egc];
                const int i1 = eidx[2 * egc + 1];
                uint4 u;
                u.x = pack2(node_params[2 * s], node_params[2 * s + 1]);
                u.y = pack2(node_params[2 * r], node_params[2 * r + 1]);
                u.z = pack2(edge_params[i0], edge_params[i1]);
                u.w = 0u;
                *(uint4*)&crow[128] = u;
            } else {
                uint4 z; z.x = z.y = z.z = z.w = 0u;
                *(uint4*)&crow[136 + (p - 1) * 8] = z;
            }
        }
        __syncthreads();

        f32x4 acc[2][4];
        #pragma unroll
        for (int mf = 0; mf < 2; ++mf)
            #pragma unroll
            for (int nf = 0; nf < 4; ++nf)
                acc[mf][nf] = (f32x4){0.f, 0.f, 0.f, 0.f};

        const unsigned short* pa = cat + (wm * 32 + lr) * CATS + lq * 8;
        #pragma unroll
        for (int ks = 0; ks < 5; ++ks) {
            const bf16x8 a0 = *(const bf16x8*)(pa + ks * 32);
            const bf16x8 a1 = *(const bf16x8*)(pa + 16 * CATS + ks * 32);
            #pragma unroll
            for (int nf = 0; nf < 4; ++nf) {
                acc[0][nf] = __builtin_amdgcn_mfma_f32_16x16x32_bf16(a0, bw1[nf][ks], acc[0][nf], 0, 0, 0);
                acc[1][nf] = __builtin_amdgcn_mfma_f32_16x16x32_bf16(a1, bw1[nf][ks], acc[1][nf], 0, 0, 0);
            }
        }
        __syncthreads();

        #pragma unroll
        for (int mf = 0; mf < 2; ++mf)
            #pragma unroll
            for (int nf = 0; nf < 4; ++nf) {
                const float bb = bias1[nf];
                #pragma unroll
                for (int r2 = 0; r2 < 4; ++r2) {
                    const float x = acc[mf][nf][r2] + bb;
                    hid[(wm * 32 + mf * 16 + lq * 4 + r2) * HS + wn * 64 + nf * 16 + lr] =
                        f2bf(silu(x));
                }
            }
        __syncthreads();

        f32x4 acc2 = (f32x4){0.f, 0.f, 0.f, 0.f};
        const unsigned short* ph = hid + (wv * 16 + lr) * HS + lq * 8;
        #pragma unroll
        for (int ks = 0; ks < 4; ++ks)
            acc2 = __builtin_amdgcn_mfma_f32_16x16x32_bf16(
                *(const bf16x8*)(ph + ks * 32), bw2[ks], acc2, 0, 0, 0);

        #pragma unroll
        for (int r2 = 0; r2 < 4; ++r2) {
            const int eg2 = ebase + wv * 16 + lq * 4 + r2;
            if (eg2 < E) {
                const int rcv = eidx[E + eg2];
                const float v = silu(acc2[r2] + bias2);
                atomicAdd(&agg[(size_t)rcv * 16 + lr], v);
            }
        }
        __syncthreads();
    }
}

// ---------------------------------------------------------------------------
extern "C" void kernel_launch(void* const* d_in, const int* in_sizes, int n_in,
                              void* d_out, int out_size, void* d_ws, size_t ws_size,
                              hipStream_t stream) {
    const float* h_i  = (const float*)d_in[0];
    const float* npar = (const float*)d_in[1];
    const float* epar = (const float*)d_in[2];
    const float* W1   = (const float*)d_in[3];
    const float* b1   = (const float*)d_in[4];
    const float* W2   = (const float*)d_in[5];
    const float* b2   = (const float*)d_in[6];
    const float* W3   = (const float*)d_in[7];
    const float* b3   = (const float*)d_in[8];
    const float* W4   = (const float*)d_in[9];
    const float* b4   = (const float*)d_in[10];
    const int*   eidx = (const int*)d_in[11];

    const int N = in_sizes[0] / 64;
    const int E = in_sizes[11] / 2;

    // workspace layout: agg | SAB(fp16 N x 256) | epk | npp
    const size_t aggB = (size_t)N * 16 * sizeof(float);
    size_t off = (aggB + 255) & ~(size_t)255;
    const size_t sabOff = off;                  off += (size_t)N * 256 * 2;
    off = (off + 255) & ~(size_t)255;
    const size_t epkOff = off;                  off += (size_t)E * 4;
    off = (off + 255) & ~(size_t)255;
    const size_t nppOff = off;                  off += (size_t)N * 4;
    const size_t need = off;

    float* agg = (float*)d_ws;
    hipMemsetAsync(agg, 0, aggB, stream);

    if (ws_size >= need) {
        unsigned short* SAB = (unsigned short*)((char*)d_ws + sabOff);
        unsigned* epk = (unsigned*)((char*)d_ws + epkOff);
        unsigned* npp = (unsigned*)((char*)d_ws + nppOff);

        k_prep<<<1024, 256, 0, stream>>>(npar, epar, eidx, npp, epk, N, E);
        k_pre<<<1024, 256, 0, stream>>>(h_i, npp, W1, b1, SAB, N);
        k_edge_v5<<<768, 256, 0, stream>>>(SAB, epk, eidx, W1, W2, b2,
                                           agg, N, E);
    } else {
        int blocks = E / 64;
        if (blocks > 768) blocks = 768;
        k_edge_v2<<<blocks, 256, 0, stream>>>(h_i, npar, epar, W1, b1, W2, b2,
                                              eidx, agg, N, E);
    }
    k_node<<<(N + 63) / 64, 64, 0, stream>>>(h_i, agg, W3, b3, W4, b4,
                                             (float*)d_out, N);
}

// Round 6
// 285.557 us; speedup vs baseline: 7.4458x; 1.1337x over previous
//
#include <hip/hip_runtime.h>
#include <math.h>

typedef __attribute__((ext_vector_type(8))) short bf16x8;
typedef __attribute__((ext_vector_type(4))) float f32x4;
typedef _Float16 half2v __attribute__((ext_vector_type(2)));
typedef _Float16 f16x8 __attribute__((ext_vector_type(8)));

__device__ __forceinline__ float silu(float x) {
    return x / (1.0f + __expf(-x));
}

__device__ __forceinline__ unsigned short f2bf(float x) {
    union { float f; unsigned u; } v; v.f = x;
    unsigned r = v.u + 0x7fffu + ((v.u >> 16) & 1u);   // RNE
    return (unsigned short)(r >> 16);
}

__device__ __forceinline__ unsigned pack2(float a, float b) {   // 2x bf16
    return (unsigned)f2bf(a) | ((unsigned)f2bf(b) << 16);
}

__device__ __forceinline__ unsigned pack2h(float a, float b) {  // 2x fp16
    half2v h; h[0] = (_Float16)a; h[1] = (_Float16)b;
    return __builtin_bit_cast(unsigned, h);
}

__device__ __forceinline__ unsigned cvt_pk(float lo, float hi) { // 2x bf16 RNE
    unsigned r;
    asm("v_cvt_pk_bf16_f32 %0, %1, %2" : "=v"(r) : "v"(lo), "v"(hi));
    return r;
}

// ---------------------------------------------------------------------------
// k_pre2 (fused): blocks [0,1024): SAB via MFMA; blocks [1024,1536): epk
//   SA[n] = h[n]@W1[0:64]   + np[n]@W1[128:130] + b1
//   SB[n] = h[n]@W1[64:128] + np[n]@W1[130:132]
// ---------------------------------------------------------------------------
__global__ __launch_bounds__(256)
void k_pre2(const float* __restrict__ h_i,
            const float* __restrict__ np,
            const float* __restrict__ ep,
            const int* __restrict__ eidx,
            const float* __restrict__ W1, const float* __restrict__ b1,
            unsigned short* __restrict__ SAB,
            unsigned* __restrict__ epk,
            int N, int E)
{
    if (blockIdx.x >= 1024) {
        // ---- epk part: faithful quirk ep[e][c] = edge_params[eidx_flat[2e+c]]
        const int tid = (blockIdx.x - 1024) * 256 + threadIdx.x;
        const int gs = 512 * 256;
        for (int i = tid; i < E; i += gs)
            epk[i] = pack2h(ep[eidx[2 * i]], ep[eidx[2 * i + 1]]);
        return;
    }

    const int t = threadIdx.x;
    const int lane = t & 63;
    const int wv = t >> 6;        // col strip: c in [wv*64, wv*64+64)
    const int lr = lane & 15;
    const int lq = lane >> 4;

    // A-frags (Wc^T): lane holds Wc[k=ks*32+lq*8+j][c=wv*64+mf*16+lr]
    bf16x8 aw[4][3];
    #pragma unroll
    for (int mf = 0; mf < 4; ++mf) {
        const int c = wv * 64 + mf * 16 + lr;
        const bool isA = c < 128;
        const int col = c & 127;
        #pragma unroll
        for (int ks = 0; ks < 3; ++ks) {
            bf16x8 w;
            #pragma unroll
            for (int j = 0; j < 8; ++j) {
                const int kl = lq * 8 + j;
                float v = 0.0f;
                if (ks < 2) {
                    const int kk = ks * 32 + kl;
                    v = W1[(size_t)(isA ? kk : 64 + kk) * 128 + col];
                } else if (kl < 2) {
                    v = W1[(size_t)((isA ? 128 : 130) + kl) * 128 + col];
                }
                w[j] = (short)f2bf(v);
            }
            aw[mf][ks] = w;
        }
    }
    float4 b1v[4];
    #pragma unroll
    for (int mf = 0; mf < 4; ++mf) {
        if (wv < 2) b1v[mf] = *(const float4*)&b1[wv * 64 + mf * 16 + lq * 4];
        else        b1v[mf] = make_float4(0.f, 0.f, 0.f, 0.f);
    }

    const int nTiles = (N + 15) / 16;
    for (int tile = blockIdx.x; tile < nTiles; tile += 1024) {
        const int n  = tile * 16 + lr;
        const int nc = (n < N) ? n : (N - 1);

        const float* hr = h_i + (size_t)nc * 64;
        bf16x8 B0, B1, B2;
        {
            float4 a0 = *(const float4*)&hr[lq * 8];
            float4 a1 = *(const float4*)&hr[lq * 8 + 4];
            float4 a2 = *(const float4*)&hr[32 + lq * 8];
            float4 a3 = *(const float4*)&hr[32 + lq * 8 + 4];
            unsigned u[4];
            u[0] = pack2(a0.x, a0.y); u[1] = pack2(a0.z, a0.w);
            u[2] = pack2(a1.x, a1.y); u[3] = pack2(a1.z, a1.w);
            B0 = __builtin_bit_cast(bf16x8, *(uint4*)u);
            u[0] = pack2(a2.x, a2.y); u[1] = pack2(a2.z, a2.w);
            u[2] = pack2(a3.x, a3.y); u[3] = pack2(a3.z, a3.w);
            B1 = __builtin_bit_cast(bf16x8, *(uint4*)u);
            unsigned z[4] = {0u, 0u, 0u, 0u};
            if (lq == 0) z[0] = pack2(np[2 * nc], np[2 * nc + 1]);
            B2 = __builtin_bit_cast(bf16x8, *(uint4*)z);
        }

        f32x4 acc[4];
        #pragma unroll
        for (int mf = 0; mf < 4; ++mf) {
            acc[mf] = (f32x4){0.f, 0.f, 0.f, 0.f};
            acc[mf] = __builtin_amdgcn_mfma_f32_16x16x32_bf16(aw[mf][0], B0, acc[mf], 0, 0, 0);
            acc[mf] = __builtin_amdgcn_mfma_f32_16x16x32_bf16(aw[mf][1], B1, acc[mf], 0, 0, 0);
            acc[mf] = __builtin_amdgcn_mfma_f32_16x16x32_bf16(aw[mf][2], B2, acc[mf], 0, 0, 0);
        }

        if (n < N) {
            unsigned short* row = SAB + (size_t)n * 256;
            #pragma unroll
            for (int mf = 0; mf < 4; ++mf) {
                uint2 u;
                u.x = pack2h(acc[mf][0] + b1v[mf].x, acc[mf][1] + b1v[mf].y);
                u.y = pack2h(acc[mf][2] + b1v[mf].z, acc[mf][3] + b1v[mf].w);
                *(uint2*)&row[wv * 64 + mf * 16 + lq * 4] = u;
            }
        }
    }
}

// ---------------------------------------------------------------------------
// k_edge_v5: barrier-free, LDS-free. Each wave owns 16 edges per group.
// (unchanged structure from round 5; launched at 2048 blocks now)
// ---------------------------------------------------------------------------
__global__ __launch_bounds__(256, 3)
void k_edge_v5(const unsigned short* __restrict__ SAB,  // [N][256] fp16
               const unsigned* __restrict__ epk,        // [E] fp16 pair
               const int* __restrict__ eidx,            // flat [2E]
               const float* __restrict__ W1,
               const float* __restrict__ W2, const float* __restrict__ b2,
               float* __restrict__ agg,
               int N, int E)
{
    const int t = threadIdx.x;
    const int lane = t & 63;
    const int wv = t >> 6;
    const int lr = lane & 15;
    const int lq = lane >> 4;

    half2v wA[4][4], wB[4][4];
    #pragma unroll
    for (int ks = 0; ks < 4; ++ks)
        #pragma unroll
        for (int c = 0; c < 4; ++c) {
            const int d = ks * 32 + lq * 8 + 2 * c;
            half2v a; a[0] = (_Float16)W1[132 * 128 + d]; a[1] = (_Float16)W1[132 * 128 + d + 1];
            half2v b; b[0] = (_Float16)W1[133 * 128 + d]; b[1] = (_Float16)W1[133 * 128 + d + 1];
            wA[ks][c] = a; wB[ks][c] = b;
        }

    bf16x8 bw2[4];
    #pragma unroll
    for (int ks = 0; ks < 4; ++ks) {
        bf16x8 w;
        #pragma unroll
        for (int j = 0; j < 8; ++j) {
            const int k = ks * 32 + lq * 8 + j;
            w[j] = (short)f2bf(W2[(size_t)k * 16 + lr]);
        }
        bw2[ks] = w;
    }
    const float bias2 = b2[lr];

    const uint4* S4 = (const uint4*)SAB;
    const int nG = (E + 15) / 16;
    const int gstride = gridDim.x * 4;
    int g = blockIdx.x * 4 + wv;
    if (g >= nG) return;

    int s0, r0; unsigned ep0; int rc0[4];
    uint4 A0[4], B0[4];
    {
        const int eb = g * 16;
        const int e = eb + lr; const int ec = (e < E) ? e : (E - 1);
        s0 = eidx[ec]; r0 = eidx[E + ec]; ep0 = epk[ec];
        if (eb + 16 <= E) {
            const int4 rv = *(const int4*)&eidx[E + eb + lq * 4];
            rc0[0] = rv.x; rc0[1] = rv.y; rc0[2] = rv.z; rc0[3] = rv.w;
        } else {
            #pragma unroll
            for (int r2 = 0; r2 < 4; ++r2) {
                int e4 = eb + lq * 4 + r2;
                rc0[r2] = eidx[E + ((e4 < E) ? e4 : (E - 1))];
            }
        }
        const uint4* pa = S4 + (size_t)s0 * 32;
        const uint4* pb = S4 + (size_t)r0 * 32 + 16;
        #pragma unroll
        for (int ks = 0; ks < 4; ++ks) { A0[ks] = pa[ks * 4 + lq]; B0[ks] = pb[ks * 4 + lq]; }
    }

    for (; g < nG; g += gstride) {
        const int gn = g + gstride;
        const bool hn = gn < nG;

        int s1 = 0, r1 = 0; unsigned ep1 = 0; int rc1[4] = {0, 0, 0, 0};
        if (hn) {
            const int eb = gn * 16;
            const int e = eb + lr; const int ec = (e < E) ? e : (E - 1);
            s1 = eidx[ec]; r1 = eidx[E + ec]; ep1 = epk[ec];
            if (eb + 16 <= E) {
                const int4 rv = *(const int4*)&eidx[E + eb + lq * 4];
                rc1[0] = rv.x; rc1[1] = rv.y; rc1[2] = rv.z; rc1[3] = rv.w;
            } else {
                #pragma unroll
                for (int r2 = 0; r2 < 4; ++r2) {
                    int e4 = eb + lq * 4 + r2;
                    rc1[r2] = eidx[E + ((e4 < E) ? e4 : (E - 1))];
                }
            }
        }

        const unsigned elo = (ep0 & 0xffffu) | (ep0 << 16);
        const unsigned ehi = (ep0 >> 16) | (ep0 & 0xffff0000u);
        const half2v e0 = __builtin_bit_cast(half2v, elo);
        const half2v e1 = __builtin_bit_cast(half2v, ehi);

        bf16x8 af[4];
        #pragma unroll
        for (int ks = 0; ks < 4; ++ks) {
            unsigned w[4];
            const unsigned* ua = (const unsigned*)&A0[ks];
            const unsigned* ub = (const unsigned*)&B0[ks];
            #pragma unroll
            for (int c = 0; c < 4; ++c) {
                half2v v = __builtin_bit_cast(half2v, ua[c])
                         + __builtin_bit_cast(half2v, ub[c]);
                v = wA[ks][c] * e0 + v;
                v = wB[ks][c] * e1 + v;
                const float x0 = (float)v[0];
                const float x1 = (float)v[1];
                w[c] = cvt_pk(silu(x0), silu(x1));
            }
            af[ks] = __builtin_bit_cast(bf16x8, *(uint4*)w);
        }

        uint4 A1[4], B1[4];
        if (hn) {
            const uint4* pa = S4 + (size_t)s1 * 32;
            const uint4* pb = S4 + (size_t)r1 * 32 + 16;
            #pragma unroll
            for (int ks = 0; ks < 4; ++ks) { A1[ks] = pa[ks * 4 + lq]; B1[ks] = pb[ks * 4 + lq]; }
        }

        f32x4 acc = (f32x4){0.f, 0.f, 0.f, 0.f};
        #pragma unroll
        for (int ks = 0; ks < 4; ++ks)
            acc = __builtin_amdgcn_mfma_f32_16x16x32_bf16(af[ks], bw2[ks], acc, 0, 0, 0);

        const int eb = g * 16;
        if (eb + 16 <= E) {
            #pragma unroll
            for (int r2 = 0; r2 < 4; ++r2)
                atomicAdd(&agg[(size_t)rc0[r2] * 16 + lr], silu(acc[r2] + bias2));
        } else {
            #pragma unroll
            for (int r2 = 0; r2 < 4; ++r2)
                if (eb + lq * 4 + r2 < E)
                    atomicAdd(&agg[(size_t)rc0[r2] * 16 + lr], silu(acc[r2] + bias2));
        }

        if (hn) {
            s0 = s1; r0 = r1; ep0 = ep1;
            #pragma unroll
            for (int r2 = 0; r2 < 4; ++r2) rc0[r2] = rc1[r2];
            #pragma unroll
            for (int ks = 0; ks < 4; ++ks) { A0[ks] = A1[ks]; B0[ks] = B1[ks]; }
        }
    }
}

// ---------------------------------------------------------------------------
// k_node2: per-thread Jacobi eigh + wave-cooperative f16-MFMA MLP + V L V^T
// ---------------------------------------------------------------------------
__host__ __device__ constexpr int tix(int i, int j) {
    return (i <= j) ? (i * 8 - (i * (i + 1)) / 2 + j)
                    : (j * 8 - (j * (j + 1)) / 2 + i);
}

template <int P, int Q>
__device__ __forceinline__ void jrot(float* T, float* V) {
    const float app = T[tix(P, P)];
    const float aqq = T[tix(Q, Q)];
    const float apq = T[tix(P, Q)];

    float theta = (aqq - app) / (2.0f * apq);
    float at = fabsf(theta);
    float tt = 1.0f / (at + sqrtf(at * at + 1.0f));
    tt = (theta < 0.0f) ? -tt : tt;
    float cc = __frsqrt_rn(tt * tt + 1.0f);
    float ss = tt * cc;

    const bool skip = !(fabsf(apq) > 1e-36f);
    const float c  = skip ? 1.0f : cc;
    const float s  = skip ? 0.0f : ss;
    const float tu = skip ? 0.0f : tt;

    #pragma unroll
    for (int k = 0; k < 8; ++k) {
        if (k == P || k == Q) continue;
        const float akp = T[tix(k, P)], akq = T[tix(k, Q)];
        T[tix(k, P)] = c * akp - s * akq;
        T[tix(k, Q)] = s * akp + c * akq;
    }
    T[tix(P, P)] = app - tu * apq;
    T[tix(Q, Q)] = aqq + tu * apq;
    T[tix(P, Q)] = 0.0f;

    #pragma unroll
    for (int k = 0; k < 8; ++k) {
        const float vp = V[k * 8 + P], vq = V[k * 8 + Q];
        V[k * 8 + P] = c * vp - s * vq;
        V[k * 8 + Q] = s * vp + c * vq;
    }
}

__device__ __forceinline__ void jacobi_sweep(float* T, float* V) {
    jrot<0,1>(T,V); jrot<0,2>(T,V); jrot<0,3>(T,V); jrot<0,4>(T,V);
    jrot<0,5>(T,V); jrot<0,6>(T,V); jrot<0,7>(T,V);
    jrot<1,2>(T,V); jrot<1,3>(T,V); jrot<1,4>(T,V); jrot<1,5>(T,V);
    jrot<1,6>(T,V); jrot<1,7>(T,V);
    jrot<2,3>(T,V); jrot<2,4>(T,V); jrot<2,5>(T,V); jrot<2,6>(T,V);
    jrot<2,7>(T,V);
    jrot<3,4>(T,V); jrot<3,5>(T,V); jrot<3,6>(T,V); jrot<3,7>(T,V);
    jrot<4,5>(T,V); jrot<4,6>(T,V); jrot<4,7>(T,V);
    jrot<5,6>(T,V); jrot<5,7>(T,V);
    jrot<6,7>(T,V);
}

#define CSWAP(a, b)                                                          \
    {                                                                        \
        bool sw = eig[a] > eig[b];                                           \
        float lo = sw ? eig[b] : eig[a];                                     \
        float hi = sw ? eig[a] : eig[b];                                     \
        eig[a] = lo; eig[b] = hi;                                            \
        _Pragma("unroll")                                                    \
        for (int k = 0; k < 8; ++k) {                                        \
            float va = V[k * 8 + a], vb = V[k * 8 + b];                      \
            V[k * 8 + a] = sw ? vb : va;                                     \
            V[k * 8 + b] = sw ? va : vb;                                     \
        }                                                                    \
    }

__global__ __launch_bounds__(256)
void k_node2(const float* __restrict__ h_i,
             const float* __restrict__ agg,
             const float* __restrict__ W3, const float* __restrict__ b3,
             const float* __restrict__ W4, const float* __restrict__ b4,
             float* __restrict__ out, int N)
{
    __shared__ _Float16 fl[4][64][40];   // feats (f16), stride 40 -> 80B rows
    __shared__ _Float16 hl[4][16][136];  // hidden per batch
    __shared__ float    zl[4][64][8];

    const int t = threadIdx.x;
    const int lane = t & 63;
    const int wv = t >> 6;
    const int lr = lane & 15;
    const int lq = lane >> 4;

    const int n  = blockIdx.x * 256 + t;
    const int nc = (n < N) ? n : (N - 1);

    // ---- per-thread Jacobi eigh ----
    float T[36], V[64];
    {
        float A[64];
        const float4* src = (const float4*)(h_i + (size_t)nc * 64);
        #pragma unroll
        for (int i = 0; i < 16; ++i) ((float4*)A)[i] = src[i];
        #pragma unroll
        for (int i = 0; i < 8; ++i)
            #pragma unroll
            for (int j = 0; j < 8; ++j)
                if (i <= j) T[tix(i, j)] = A[i * 8 + j];
    }
    #pragma unroll
    for (int i = 0; i < 64; ++i) V[i] = 0.0f;
    #pragma unroll
    for (int i = 0; i < 8; ++i) V[i * 8 + i] = 1.0f;

    #pragma unroll 1
    for (int sw = 0; sw < 5; ++sw) jacobi_sweep(T, V);

    float eig[8];
    #pragma unroll
    for (int i = 0; i < 8; ++i) eig[i] = T[tix(i, i)];

    CSWAP(0,1) CSWAP(2,3) CSWAP(4,5) CSWAP(6,7)
    CSWAP(0,2) CSWAP(1,3) CSWAP(4,6) CSWAP(5,7)
    CSWAP(1,2) CSWAP(5,6)
    CSWAP(0,4) CSWAP(1,5) CSWAP(2,6) CSWAP(3,7)
    CSWAP(2,4) CSWAP(3,5)
    CSWAP(1,2) CSWAP(3,4) CSWAP(5,6)

    // ---- W3/W4 f16 fragments (loaded once; lane-varying -> vector loads) ----
    f16x8 w3f[8];
    #pragma unroll
    for (int nf = 0; nf < 8; ++nf) {
        f16x8 w;
        #pragma unroll
        for (int j = 0; j < 8; ++j)
            w[j] = (_Float16)W3[(size_t)(lq * 8 + j) * 128 + nf * 16 + lr];
        w3f[nf] = w;
    }
    f16x8 w4f[4];
    #pragma unroll
    for (int ks = 0; ks < 4; ++ks) {
        f16x8 w;
        #pragma unroll
        for (int j = 0; j < 8; ++j)
            w[j] = (lr < 8) ? (_Float16)W4[(size_t)(ks * 32 + lq * 8 + j) * 8 + lr]
                            : (_Float16)0.0f;
        w4f[ks] = w;
    }
    float b3v[8];
    #pragma unroll
    for (int nf = 0; nf < 8; ++nf) b3v[nf] = b3[nf * 16 + lr];
    const float b4v = (lr < 8) ? b4[lr] : 0.0f;

    // ---- feats = [agg(16) | eig(8) | 1.0 x8] -> LDS (f16) ----
    {
        float f[32];
        const float4* ag = (const float4*)(agg + (size_t)nc * 16);
        #pragma unroll
        for (int i = 0; i < 4; ++i) {
            float4 v = ag[i];
            f[i * 4 + 0] = v.x; f[i * 4 + 1] = v.y;
            f[i * 4 + 2] = v.z; f[i * 4 + 3] = v.w;
        }
        #pragma unroll
        for (int i = 0; i < 8; ++i) f[16 + i] = eig[i];
        #pragma unroll
        for (int i = 0; i < 8; ++i) f[24 + i] = 1.0f;

        unsigned* dst = (unsigned*)&fl[wv][lane][0];
        #pragma unroll
        for (int i = 0; i < 16; ++i) dst[i] = pack2h(f[2 * i], f[2 * i + 1]);
    }
    __syncthreads();

    // ---- MLP: 4 batches of 16 nodes per wave ----
    #pragma unroll 1
    for (int b = 0; b < 4; ++b) {
        const f16x8 a1 = *(const f16x8*)&fl[wv][b * 16 + lr][lq * 8];
        f32x4 acc1[8];
        #pragma unroll
        for (int nf = 0; nf < 8; ++nf) {
            acc1[nf] = (f32x4){0.f, 0.f, 0.f, 0.f};
            acc1[nf] = __builtin_amdgcn_mfma_f32_16x16x32_f16(a1, w3f[nf], acc1[nf], 0, 0, 0);
        }
        #pragma unroll
        for (int nf = 0; nf < 8; ++nf)
            #pragma unroll
            for (int r2 = 0; r2 < 4; ++r2) {
                const float x = acc1[nf][r2] + b3v[nf];
                hl[wv][lq * 4 + r2][nf * 16 + lr] = (_Float16)silu(x);
            }
        __syncthreads();

        f32x4 acc2 = (f32x4){0.f, 0.f, 0.f, 0.f};
        #pragma unroll
        for (int ks = 0; ks < 4; ++ks) {
            const f16x8 a2 = *(const f16x8*)&hl[wv][lr][ks * 32 + lq * 8];
            acc2 = __builtin_amdgcn_mfma_f32_16x16x32_f16(a2, w4f[ks], acc2, 0, 0, 0);
        }
        if (lr < 8) {
            #pragma unroll
            for (int r2 = 0; r2 < 4; ++r2)
                zl[wv][b * 16 + lq * 4 + r2][lr] = acc2[r2] + b4v;
        }
        __syncthreads();
    }

    // ---- softmax + V diag(lam) V^T (per-thread) ----
    float z[8];
    {
        float4 z0 = *(const float4*)&zl[wv][lane][0];
        float4 z1 = *(const float4*)&zl[wv][lane][4];
        z[0] = z0.x; z[1] = z0.y; z[2] = z0.z; z[3] = z0.w;
        z[4] = z1.x; z[5] = z1.y; z[6] = z1.z; z[7] = z1.w;
    }
    float m = z[0];
    #pragma unroll
    for (int o = 1; o < 8; ++o) m = fmaxf(m, z[o]);
    float lam[8], den = 0.0f;
    #pragma unroll
    for (int o = 0; o < 8; ++o) { lam[o] = __expf(z[o] - m); den += lam[o]; }
    const float inv = 1.0f / den;
    #pragma unroll
    for (int o = 0; o < 8; ++o) lam[o] *= inv;

    if (n < N) {
        float* orow = out + (size_t)n * 64;
        #pragma unroll
        for (int i = 0; i < 8; ++i) {
            float si[8];
            #pragma unroll
            for (int j = 0; j < 8; ++j) si[j] = lam[j] * V[i * 8 + j];
            float r[8];
            #pragma unroll
            for (int k = 0; k < 8; ++k) {
                float sum = 0.0f;
                #pragma unroll
                for (int j = 0; j < 8; ++j) sum += si[j] * V[k * 8 + j];
                r[k] = sum;
            }
            ((float4*)orow)[i * 2 + 0] = make_float4(r[0], r[1], r[2], r[3]);
            ((float4*)orow)[i * 2 + 1] = make_float4(r[4], r[5], r[6], r[7]);
        }
    }
}

// ---------------------------------------------------------------------------
// Fallback edge kernel (round-2 style, raw fp32 inputs, needs only agg in ws)
// ---------------------------------------------------------------------------
#define CATS 168
#define HS   136
__global__ __launch_bounds__(256, 2)
void k_edge_v2(const float* __restrict__ h_i,
               const float* __restrict__ node_params,
               const float* __restrict__ edge_params,
               const float* __restrict__ W1, const float* __restrict__ b1,
               const float* __restrict__ W2, const float* __restrict__ b2,
               const int* __restrict__ eidx,
               float* __restrict__ agg,
               int N, int E)
{
    __shared__ unsigned short smem[23680];
    unsigned short* w1t = smem;
    unsigned short* w2t = smem + 128 * CATS;
    unsigned short* cat = smem;
    unsigned short* hid = smem + 64 * CATS;

    const int t = threadIdx.x;
    const int lane = t & 63;
    const int wv = t >> 6;
    const int wn = wv & 1;
    const int wm = wv >> 1;
    const int lr = lane & 15;
    const int lq = lane >> 4;

    for (int idx = t; idx < 128 * 80; idx += 256) {
        const int col = idx & 127, kp = idx >> 7;
        const int k0 = 2 * kp;
        float f0 = (k0     < 134) ? W1[(size_t)k0       * 128 + col] : 0.0f;
        float f1 = (k0 + 1 < 134) ? W1[(size_t)(k0 + 1) * 128 + col] : 0.0f;
        *(unsigned*)&w1t[col * CATS + k0] = pack2(f0, f1);
    }
    for (int idx = t; idx < 16 * 64; idx += 256) {
        const int col = idx & 15, kp = idx >> 4;
        const int k0 = 2 * kp;
        *(unsigned*)&w2t[col * HS + k0] =
            pack2(W2[(size_t)k0 * 16 + col], W2[(size_t)(k0 + 1) * 16 + col]);
    }
    __syncthreads();

    bf16x8 bw1[4][5];
    #pragma unroll
    for (int nf = 0; nf < 4; ++nf)
        #pragma unroll
        for (int ks = 0; ks < 5; ++ks)
            bw1[nf][ks] = *(const bf16x8*)&w1t[(wn * 64 + nf * 16 + lr) * CATS + ks * 32 + lq * 8];
    bf16x8 bw2[4];
    #pragma unroll
    for (int ks = 0; ks < 4; ++ks)
        bw2[ks] = *(const bf16x8*)&w2t[lr * HS + ks * 32 + lq * 8];

    float bias1[4];
    #pragma unroll
    for (int nf = 0; nf < 4; ++nf) bias1[nf] = b1[wn * 64 + nf * 16 + lr];
    const float bias2 = b2[lr];
    __syncthreads();

    const int el = t >> 2;
    const int p  = t & 3;

    const int nTiles = E / 64;
    for (int tile = blockIdx.x; tile < nTiles; tile += gridDim.x) {
        const int ebase = tile * 64;
        {
            const int eg  = ebase + el;
            const int egc = (eg < E) ? eg : (E - 1);
            const int s = eidx[egc];
            const int r = eidx[E + egc];
            const float4* hs = (const float4*)(h_i + (size_t)s * 64);
            const float4* hr = (const float4*)(h_i + (size_t)r * 64);
            unsigned short* crow = cat + el * CATS;
            #pragma unroll
            for (int m = 0; m < 8; ++m) {
                const int q = p + 4 * m;
                float4 v = (q < 16) ? hs[q] : hr[q - 16];
                uint2 u; u.x = pack2(v.x, v.y); u.y = pack2(v.z, v.w);
                *(uint2*)&crow[q * 4] = u;
            }
            if (p == 0) {
                const int i0 = eidx[2 * egc];
                const int i1 = eidx[2 * egc + 1];
                uint4 u;
                u.x = pack2(node_params[2 * s], node_params[2 * s + 1]);
                u.y = pack2(node_params[2 * r], node_params[2 * r + 1]);
                u.z = pack2(edge_params[i0], edge_params[i1]);
                u.w = 0u;
                *(uint4*)&crow[128] = u;
            } else {
                uint4 z; z.x = z.y = z.z = z.w = 0u;
                *(uint4*)&crow[136 + (p - 1) * 8] = z;
            }
        }
        __syncthreads();

        f32x4 acc[2][4];
        #pragma unroll
        for (int mf = 0; mf < 2; ++mf)
            #pragma unroll
            for (int nf = 0; nf < 4; ++nf)
                acc[mf][nf] = (f32x4){0.f, 0.f, 0.f, 0.f};

        const unsigned short* pa = cat + (wm * 32 + lr) * CATS + lq * 8;
        #pragma unroll
        for (int ks = 0; ks < 5; ++ks) {
            const bf16x8 a0 = *(const bf16x8*)(pa + ks * 32);
            const bf16x8 a1 = *(const bf16x8*)(pa + 16 * CATS + ks * 32);
            #pragma unroll
            for (int nf = 0; nf < 4; ++nf) {
                acc[0][nf] = __builtin_amdgcn_mfma_f32_16x16x32_bf16(a0, bw1[nf][ks], acc[0][nf], 0, 0, 0);
                acc[1][nf] = __builtin_amdgcn_mfma_f32_16x16x32_bf16(a1, bw1[nf][ks], acc[1][nf], 0, 0, 0);
            }
        }
        __syncthreads();

        #pragma unroll
        for (int mf = 0; mf < 2; ++mf)
            #pragma unroll
            for (int nf = 0; nf < 4; ++nf) {
                const float bb = bias1[nf];
                #pragma unroll
                for (int r2 = 0; r2 < 4; ++r2) {
                    const float x = acc[mf][nf][r2] + bb;
                    hid[(wm * 32 + mf * 16 + lq * 4 + r2) * HS + wn * 64 + nf * 16 + lr] =
                        f2bf(silu(x));
                }
            }
        __syncthreads();

        f32x4 acc2 = (f32x4){0.f, 0.f, 0.f, 0.f};
        const unsigned short* ph = hid + (wv * 16 + lr) * HS + lq * 8;
        #pragma unroll
        for (int ks = 0; ks < 4; ++ks)
            acc2 = __builtin_amdgcn_mfma_f32_16x16x32_bf16(
                *(const bf16x8*)(ph + ks * 32), bw2[ks], acc2, 0, 0, 0);

        #pragma unroll
        for (int r2 = 0; r2 < 4; ++r2) {
            const int eg2 = ebase + wv * 16 + lq * 4 + r2;
            if (eg2 < E) {
                const int rcv = eidx[E + eg2];
                const float v = silu(acc2[r2] + bias2);
                atomicAdd(&agg[(size_t)rcv * 16 + lr], v);
            }
        }
        __syncthreads();
    }
}

// ---------------------------------------------------------------------------
extern "C" void kernel_launch(void* const* d_in, const int* in_sizes, int n_in,
                              void* d_out, int out_size, void* d_ws, size_t ws_size,
                              hipStream_t stream) {
    const float* h_i  = (const float*)d_in[0];
    const float* npar = (const float*)d_in[1];
    const float* epar = (const float*)d_in[2];
    const float* W1   = (const float*)d_in[3];
    const float* b1   = (const float*)d_in[4];
    const float* W2   = (const float*)d_in[5];
    const float* b2   = (const float*)d_in[6];
    const float* W3   = (const float*)d_in[7];
    const float* b3   = (const float*)d_in[8];
    const float* W4   = (const float*)d_in[9];
    const float* b4   = (const float*)d_in[10];
    const int*   eidx = (const int*)d_in[11];

    const int N = in_sizes[0] / 64;
    const int E = in_sizes[11] / 2;

    // workspace layout: agg | SAB(fp16 N x 256) | epk
    const size_t aggB = (size_t)N * 16 * sizeof(float);
    size_t off = (aggB + 255) & ~(size_t)255;
    const size_t sabOff = off;                  off += (size_t)N * 256 * 2;
    off = (off + 255) & ~(size_t)255;
    const size_t epkOff = off;                  off += (size_t)E * 4;
    const size_t need = off;

    float* agg = (float*)d_ws;
    hipMemsetAsync(agg, 0, aggB, stream);

    if (ws_size >= need) {
        unsigned short* SAB = (unsigned short*)((char*)d_ws + sabOff);
        unsigned* epk = (unsigned*)((char*)d_ws + epkOff);

        k_pre2<<<1536, 256, 0, stream>>>(h_i, npar, epar, eidx, W1, b1,
                                         SAB, epk, N, E);
        k_edge_v5<<<2048, 256, 0, stream>>>(SAB, epk, eidx, W1, W2, b2,
                                            agg, N, E);
    } else {
        int blocks = E / 64;
        if (blocks > 768) blocks = 768;
        k_edge_v2<<<blocks, 256, 0, stream>>>(h_i, npar, epar, W1, b1, W2, b2,
                                              eidx, agg, N, E);
    }
    k_node2<<<(N + 255) / 256, 256, 0, stream>>>(h_i, agg, W3, b3, W4, b4,
                                                 (float*)d_out, N);
}

// Round 10
// 282.173 us; speedup vs baseline: 7.5351x; 1.0120x over previous
//
#include <hip/hip_runtime.h>
#include <math.h>

typedef __attribute__((ext_vector_type(8))) short bf16x8;
typedef __attribute__((ext_vector_type(4))) float f32x4;
typedef _Float16 half2v __attribute__((ext_vector_type(2)));
typedef _Float16 f16x8 __attribute__((ext_vector_type(8)));

__device__ __forceinline__ float silu(float x) {
    return x / (1.0f + __expf(-x));
}

__device__ __forceinline__ unsigned short f2bf(float x) {
    union { float f; unsigned u; } v; v.f = x;
    unsigned r = v.u + 0x7fffu + ((v.u >> 16) & 1u);   // RNE
    return (unsigned short)(r >> 16);
}

__device__ __forceinline__ unsigned pack2(float a, float b) {   // 2x bf16
    return (unsigned)f2bf(a) | ((unsigned)f2bf(b) << 16);
}

__device__ __forceinline__ unsigned pack2h(float a, float b) {  // 2x fp16
    half2v h; h[0] = (_Float16)a; h[1] = (_Float16)b;
    return __builtin_bit_cast(unsigned, h);
}

__device__ __forceinline__ unsigned cvt_pk(float lo, float hi) { // 2x bf16 RNE
    unsigned r;
    asm("v_cvt_pk_bf16_f32 %0, %1, %2" : "=v"(r) : "v"(lo), "v"(hi));
    return r;
}

// ---------------------------------------------------------------------------
// k_pre2 (fused): blocks [0,1024): SAB via MFMA; blocks [1024,1536): epk
//   SA[n] = h[n]@W1[0:64]   + np[n]@W1[128:130] + b1
//   SB[n] = h[n]@W1[64:128] + np[n]@W1[130:132]
// (byte-identical to round-6 passing version)
// ---------------------------------------------------------------------------
__global__ __launch_bounds__(256)
void k_pre2(const float* __restrict__ h_i,
            const float* __restrict__ np,
            const float* __restrict__ ep,
            const int* __restrict__ eidx,
            const float* __restrict__ W1, const float* __restrict__ b1,
            unsigned short* __restrict__ SAB,
            unsigned* __restrict__ epk,
            int N, int E)
{
    if (blockIdx.x >= 1024) {
        const int tid = (blockIdx.x - 1024) * 256 + threadIdx.x;
        const int gs = 512 * 256;
        for (int i = tid; i < E; i += gs)
            epk[i] = pack2h(ep[eidx[2 * i]], ep[eidx[2 * i + 1]]);  // faithful quirk
        return;
    }

    const int t = threadIdx.x;
    const int lane = t & 63;
    const int wv = t >> 6;
    const int lr = lane & 15;
    const int lq = lane >> 4;

    bf16x8 aw[4][3];
    #pragma unroll
    for (int mf = 0; mf < 4; ++mf) {
        const int c = wv * 64 + mf * 16 + lr;
        const bool isA = c < 128;
        const int col = c & 127;
        #pragma unroll
        for (int ks = 0; ks < 3; ++ks) {
            bf16x8 w;
            #pragma unroll
            for (int j = 0; j < 8; ++j) {
                const int kl = lq * 8 + j;
                float v = 0.0f;
                if (ks < 2) {
                    const int kk = ks * 32 + kl;
                    v = W1[(size_t)(isA ? kk : 64 + kk) * 128 + col];
                } else if (kl < 2) {
                    v = W1[(size_t)((isA ? 128 : 130) + kl) * 128 + col];
                }
                w[j] = (short)f2bf(v);
            }
            aw[mf][ks] = w;
        }
    }
    float4 b1v[4];
    #pragma unroll
    for (int mf = 0; mf < 4; ++mf) {
        if (wv < 2) b1v[mf] = *(const float4*)&b1[wv * 64 + mf * 16 + lq * 4];
        else        b1v[mf] = make_float4(0.f, 0.f, 0.f, 0.f);
    }

    const int nTiles = (N + 15) / 16;
    for (int tile = blockIdx.x; tile < nTiles; tile += 1024) {
        const int n  = tile * 16 + lr;
        const int nc = (n < N) ? n : (N - 1);

        const float* hr = h_i + (size_t)nc * 64;
        bf16x8 B0, B1, B2;
        {
            float4 a0 = *(const float4*)&hr[lq * 8];
            float4 a1 = *(const float4*)&hr[lq * 8 + 4];
            float4 a2 = *(const float4*)&hr[32 + lq * 8];
            float4 a3 = *(const float4*)&hr[32 + lq * 8 + 4];
            unsigned u[4];
            u[0] = pack2(a0.x, a0.y); u[1] = pack2(a0.z, a0.w);
            u[2] = pack2(a1.x, a1.y); u[3] = pack2(a1.z, a1.w);
            B0 = __builtin_bit_cast(bf16x8, *(uint4*)u);
            u[0] = pack2(a2.x, a2.y); u[1] = pack2(a2.z, a2.w);
            u[2] = pack2(a3.x, a3.y); u[3] = pack2(a3.z, a3.w);
            B1 = __builtin_bit_cast(bf16x8, *(uint4*)u);
            unsigned z[4] = {0u, 0u, 0u, 0u};
            if (lq == 0) z[0] = pack2(np[2 * nc], np[2 * nc + 1]);
            B2 = __builtin_bit_cast(bf16x8, *(uint4*)z);
        }

        f32x4 acc[4];
        #pragma unroll
        for (int mf = 0; mf < 4; ++mf) {
            acc[mf] = (f32x4){0.f, 0.f, 0.f, 0.f};
            acc[mf] = __builtin_amdgcn_mfma_f32_16x16x32_bf16(aw[mf][0], B0, acc[mf], 0, 0, 0);
            acc[mf] = __builtin_amdgcn_mfma_f32_16x16x32_bf16(aw[mf][1], B1, acc[mf], 0, 0, 0);
            acc[mf] = __builtin_amdgcn_mfma_f32_16x16x32_bf16(aw[mf][2], B2, acc[mf], 0, 0, 0);
        }

        if (n < N) {
            unsigned short* row = SAB + (size_t)n * 256;
            #pragma unroll
            for (int mf = 0; mf < 4; ++mf) {
                uint2 u;
                u.x = pack2h(acc[mf][0] + b1v[mf].x, acc[mf][1] + b1v[mf].y);
                u.y = pack2h(acc[mf][2] + b1v[mf].z, acc[mf][3] + b1v[mf].w);
                *(uint2*)&row[wv * 64 + mf * 16 + lq * 4] = u;
            }
        }
    }
}

// ---------------------------------------------------------------------------
// k_edge_v5: barrier-free, LDS-free. Each wave owns 16 edges per group.
// (byte-identical to round-6 PASSING version: conditional prefetch,
//  f32 silu, cvt_pk bf16 A-frags, bf16 MFMA layer 2)
// ---------------------------------------------------------------------------
__global__ __launch_bounds__(256, 3)
void k_edge_v5(const unsigned short* __restrict__ SAB,  // [N][256] fp16
               const unsigned* __restrict__ epk,        // [E] fp16 pair
               const int* __restrict__ eidx,            // flat [2E]
               const float* __restrict__ W1,
               const float* __restrict__ W2, const float* __restrict__ b2,
               float* __restrict__ agg,
               int N, int E)
{
    const int t = threadIdx.x;
    const int lane = t & 63;
    const int wv = t >> 6;
    const int lr = lane & 15;
    const int lq = lane >> 4;

    half2v wA[4][4], wB[4][4];
    #pragma unroll
    for (int ks = 0; ks < 4; ++ks)
        #pragma unroll
        for (int c = 0; c < 4; ++c) {
            const int d = ks * 32 + lq * 8 + 2 * c;
            half2v a; a[0] = (_Float16)W1[132 * 128 + d]; a[1] = (_Float16)W1[132 * 128 + d + 1];
            half2v b; b[0] = (_Float16)W1[133 * 128 + d]; b[1] = (_Float16)W1[133 * 128 + d + 1];
            wA[ks][c] = a; wB[ks][c] = b;
        }

    bf16x8 bw2[4];
    #pragma unroll
    for (int ks = 0; ks < 4; ++ks) {
        bf16x8 w;
        #pragma unroll
        for (int j = 0; j < 8; ++j) {
            const int k = ks * 32 + lq * 8 + j;
            w[j] = (short)f2bf(W2[(size_t)k * 16 + lr]);
        }
        bw2[ks] = w;
    }
    const float bias2 = b2[lr];

    const uint4* S4 = (const uint4*)SAB;
    const int nG = (E + 15) / 16;
    const int gstride = gridDim.x * 4;
    int g = blockIdx.x * 4 + wv;
    if (g >= nG) return;

    int s0, r0; unsigned ep0; int rc0[4];
    uint4 A0[4], B0[4];
    {
        const int eb = g * 16;
        const int e = eb + lr; const int ec = (e < E) ? e : (E - 1);
        s0 = eidx[ec]; r0 = eidx[E + ec]; ep0 = epk[ec];
        if (eb + 16 <= E) {
            const int4 rv = *(const int4*)&eidx[E + eb + lq * 4];
            rc0[0] = rv.x; rc0[1] = rv.y; rc0[2] = rv.z; rc0[3] = rv.w;
        } else {
            #pragma unroll
            for (int r2 = 0; r2 < 4; ++r2) {
                int e4 = eb + lq * 4 + r2;
                rc0[r2] = eidx[E + ((e4 < E) ? e4 : (E - 1))];
            }
        }
        const uint4* pa = S4 + (size_t)s0 * 32;
        const uint4* pb = S4 + (size_t)r0 * 32 + 16;
        #pragma unroll
        for (int ks = 0; ks < 4; ++ks) { A0[ks] = pa[ks * 4 + lq]; B0[ks] = pb[ks * 4 + lq]; }
    }

    for (; g < nG; g += gstride) {
        const int gn = g + gstride;
        const bool hn = gn < nG;

        int s1 = 0, r1 = 0; unsigned ep1 = 0; int rc1[4] = {0, 0, 0, 0};
        if (hn) {
            const int eb = gn * 16;
            const int e = eb + lr; const int ec = (e < E) ? e : (E - 1);
            s1 = eidx[ec]; r1 = eidx[E + ec]; ep1 = epk[ec];
            if (eb + 16 <= E) {
                const int4 rv = *(const int4*)&eidx[E + eb + lq * 4];
                rc1[0] = rv.x; rc1[1] = rv.y; rc1[2] = rv.z; rc1[3] = rv.w;
            } else {
                #pragma unroll
                for (int r2 = 0; r2 < 4; ++r2) {
                    int e4 = eb + lq * 4 + r2;
                    rc1[r2] = eidx[E + ((e4 < E) ? e4 : (E - 1))];
                }
            }
        }

        const unsigned elo = (ep0 & 0xffffu) | (ep0 << 16);
        const unsigned ehi = (ep0 >> 16) | (ep0 & 0xffff0000u);
        const half2v e0 = __builtin_bit_cast(half2v, elo);
        const half2v e1 = __builtin_bit_cast(half2v, ehi);

        bf16x8 af[4];
        #pragma unroll
        for (int ks = 0; ks < 4; ++ks) {
            unsigned w[4];
            const unsigned* ua = (const unsigned*)&A0[ks];
            const unsigned* ub = (const unsigned*)&B0[ks];
            #pragma unroll
            for (int c = 0; c < 4; ++c) {
                half2v v = __builtin_bit_cast(half2v, ua[c])
                         + __builtin_bit_cast(half2v, ub[c]);
                v = wA[ks][c] * e0 + v;
                v = wB[ks][c] * e1 + v;
                const float x0 = (float)v[0];
                const float x1 = (float)v[1];
                w[c] = cvt_pk(silu(x0), silu(x1));
            }
            af[ks] = __builtin_bit_cast(bf16x8, *(uint4*)w);
        }

        uint4 A1[4], B1[4];
        if (hn) {
            const uint4* pa = S4 + (size_t)s1 * 32;
            const uint4* pb = S4 + (size_t)r1 * 32 + 16;
            #pragma unroll
            for (int ks = 0; ks < 4; ++ks) { A1[ks] = pa[ks * 4 + lq]; B1[ks] = pb[ks * 4 + lq]; }
        }

        f32x4 acc = (f32x4){0.f, 0.f, 0.f, 0.f};
        #pragma unroll
        for (int ks = 0; ks < 4; ++ks)
            acc = __builtin_amdgcn_mfma_f32_16x16x32_bf16(af[ks], bw2[ks], acc, 0, 0, 0);

        const int eb = g * 16;
        if (eb + 16 <= E) {
            #pragma unroll
            for (int r2 = 0; r2 < 4; ++r2)
                atomicAdd(&agg[(size_t)rc0[r2] * 16 + lr], silu(acc[r2] + bias2));
        } else {
            #pragma unroll
            for (int r2 = 0; r2 < 4; ++r2)
                if (eb + lq * 4 + r2 < E)
                    atomicAdd(&agg[(size_t)rc0[r2] * 16 + lr], silu(acc[r2] + bias2));
        }

        if (hn) {
            s0 = s1; r0 = r1; ep0 = ep1;
            #pragma unroll
            for (int r2 = 0; r2 < 4; ++r2) rc0[r2] = rc1[r2];
            #pragma unroll
            for (int ks = 0; ks < 4; ++ks) { A0[ks] = A1[ks]; B0[ks] = B1[ks]; }
        }
    }
}

// ---------------------------------------------------------------------------
// k_node2h: 128-thread (2-wave) blocks. Identical math to round-6's passing
// k_node2 (256-thread); only the wv dimension shrinks 4 -> 2 for better
// CU load balance (782 blocks vs 391). Multi-wave barrier retained.
// ---------------------------------------------------------------------------
__host__ __device__ constexpr int tix(int i, int j) {
    return (i <= j) ? (i * 8 - (i * (i + 1)) / 2 + j)
                    : (j * 8 - (j * (j + 1)) / 2 + i);
}

template <int P, int Q>
__device__ __forceinline__ void jrot(float* T, float* V) {
    const float app = T[tix(P, P)];
    const float aqq = T[tix(Q, Q)];
    const float apq = T[tix(P, Q)];

    float theta = (aqq - app) / (2.0f * apq);
    float at = fabsf(theta);
    float tt = 1.0f / (at + sqrtf(at * at + 1.0f));
    tt = (theta < 0.0f) ? -tt : tt;
    float cc = __frsqrt_rn(tt * tt + 1.0f);
    float ss = tt * cc;

    const bool skip = !(fabsf(apq) > 1e-36f);
    const float c  = skip ? 1.0f : cc;
    const float s  = skip ? 0.0f : ss;
    const float tu = skip ? 0.0f : tt;

    #pragma unroll
    for (int k = 0; k < 8; ++k) {
        if (k == P || k == Q) continue;
        const float akp = T[tix(k, P)], akq = T[tix(k, Q)];
        T[tix(k, P)] = c * akp - s * akq;
        T[tix(k, Q)] = s * akp + c * akq;
    }
    T[tix(P, P)] = app - tu * apq;
    T[tix(Q, Q)] = aqq + tu * apq;
    T[tix(P, Q)] = 0.0f;

    #pragma unroll
    for (int k = 0; k < 8; ++k) {
        const float vp = V[k * 8 + P], vq = V[k * 8 + Q];
        V[k * 8 + P] = c * vp - s * vq;
        V[k * 8 + Q] = s * vp + c * vq;
    }
}

__device__ __forceinline__ void jacobi_sweep(float* T, float* V) {
    jrot<0,1>(T,V); jrot<0,2>(T,V); jrot<0,3>(T,V); jrot<0,4>(T,V);
    jrot<0,5>(T,V); jrot<0,6>(T,V); jrot<0,7>(T,V);
    jrot<1,2>(T,V); jrot<1,3>(T,V); jrot<1,4>(T,V); jrot<1,5>(T,V);
    jrot<1,6>(T,V); jrot<1,7>(T,V);
    jrot<2,3>(T,V); jrot<2,4>(T,V); jrot<2,5>(T,V); jrot<2,6>(T,V);
    jrot<2,7>(T,V);
    jrot<3,4>(T,V); jrot<3,5>(T,V); jrot<3,6>(T,V); jrot<3,7>(T,V);
    jrot<4,5>(T,V); jrot<4,6>(T,V); jrot<4,7>(T,V);
    jrot<5,6>(T,V); jrot<5,7>(T,V);
    jrot<6,7>(T,V);
}

#define CSWAP(a, b)                                                          \
    {                                                                        \
        bool sw = eig[a] > eig[b];                                           \
        float lo = sw ? eig[b] : eig[a];                                     \
        float hi = sw ? eig[a] : eig[b];                                     \
        eig[a] = lo; eig[b] = hi;                                            \
        _Pragma("unroll")                                                    \
        for (int k = 0; k < 8; ++k) {                                        \
            float va = V[k * 8 + a], vb = V[k * 8 + b];                      \
            V[k * 8 + a] = sw ? vb : va;                                     \
            V[k * 8 + b] = sw ? va : vb;                                     \
        }                                                                    \
    }

__global__ __launch_bounds__(128)
void k_node2h(const float* __restrict__ h_i,
              const float* __restrict__ agg,
              const float* __restrict__ W3, const float* __restrict__ b3,
              const float* __restrict__ W4, const float* __restrict__ b4,
              float* __restrict__ out, int N)
{
    __shared__ _Float16 fl[2][64][40];
    __shared__ _Float16 hl[2][16][136];
    __shared__ float    zl[2][64][8];

    const int t = threadIdx.x;
    const int lane = t & 63;
    const int wv = t >> 6;        // 0..1
    const int lr = lane & 15;
    const int lq = lane >> 4;

    const int n  = blockIdx.x * 128 + t;
    const int nc = (n < N) ? n : (N - 1);

    float T[36], V[64];
    {
        float A[64];
        const float4* src = (const float4*)(h_i + (size_t)nc * 64);
        #pragma unroll
        for (int i = 0; i < 16; ++i) ((float4*)A)[i] = src[i];
        #pragma unroll
        for (int i = 0; i < 8; ++i)
            #pragma unroll
            for (int j = 0; j < 8; ++j)
                if (i <= j) T[tix(i, j)] = A[i * 8 + j];
    }
    #pragma unroll
    for (int i = 0; i < 64; ++i) V[i] = 0.0f;
    #pragma unroll
    for (int i = 0; i < 8; ++i) V[i * 8 + i] = 1.0f;

    #pragma unroll 1
    for (int sw = 0; sw < 5; ++sw) jacobi_sweep(T, V);

    float eig[8];
    #pragma unroll
    for (int i = 0; i < 8; ++i) eig[i] = T[tix(i, i)];

    CSWAP(0,1) CSWAP(2,3) CSWAP(4,5) CSWAP(6,7)
    CSWAP(0,2) CSWAP(1,3) CSWAP(4,6) CSWAP(5,7)
    CSWAP(1,2) CSWAP(5,6)
    CSWAP(0,4) CSWAP(1,5) CSWAP(2,6) CSWAP(3,7)
    CSWAP(2,4) CSWAP(3,5)
    CSWAP(1,2) CSWAP(3,4) CSWAP(5,6)

    // W3/W4 f16 fragments
    f16x8 w3f[8];
    #pragma unroll
    for (int nf = 0; nf < 8; ++nf) {
        f16x8 w;
        #pragma unroll
        for (int j = 0; j < 8; ++j)
            w[j] = (_Float16)W3[(size_t)(lq * 8 + j) * 128 + nf * 16 + lr];
        w3f[nf] = w;
    }
    f16x8 w4f[4];
    #pragma unroll
    for (int ks = 0; ks < 4; ++ks) {
        f16x8 w;
        #pragma unroll
        for (int j = 0; j < 8; ++j)
            w[j] = (lr < 8) ? (_Float16)W4[(size_t)(ks * 32 + lq * 8 + j) * 8 + lr]
                            : (_Float16)0.0f;
        w4f[ks] = w;
    }
    float b3v[8];
    #pragma unroll
    for (int nf = 0; nf < 8; ++nf) b3v[nf] = b3[nf * 16 + lr];
    const float b4v = (lr < 8) ? b4[lr] : 0.0f;

    // feats = [agg(16) | eig(8) | 1.0 x8] -> LDS (f16)
    {
        float f[32];
        const float4* ag = (const float4*)(agg + (size_t)nc * 16);
        #pragma unroll
        for (int i = 0; i < 4; ++i) {
            float4 v = ag[i];
            f[i * 4 + 0] = v.x; f[i * 4 + 1] = v.y;
            f[i * 4 + 2] = v.z; f[i * 4 + 3] = v.w;
        }
        #pragma unroll
        for (int i = 0; i < 8; ++i) f[16 + i] = eig[i];
        #pragma unroll
        for (int i = 0; i < 8; ++i) f[24 + i] = 1.0f;

        unsigned* dst = (unsigned*)&fl[wv][lane][0];
        #pragma unroll
        for (int i = 0; i < 16; ++i) dst[i] = pack2h(f[2 * i], f[2 * i + 1]);
    }
    __syncthreads();

    #pragma unroll 1
    for (int b = 0; b < 4; ++b) {
        const f16x8 a1 = *(const f16x8*)&fl[wv][b * 16 + lr][lq * 8];
        f32x4 acc1[8];
        #pragma unroll
        for (int nf = 0; nf < 8; ++nf) {
            acc1[nf] = (f32x4){0.f, 0.f, 0.f, 0.f};
            acc1[nf] = __builtin_amdgcn_mfma_f32_16x16x32_f16(a1, w3f[nf], acc1[nf], 0, 0, 0);
        }
        #pragma unroll
        for (int nf = 0; nf < 8; ++nf)
            #pragma unroll
            for (int r2 = 0; r2 < 4; ++r2) {
                const float x = acc1[nf][r2] + b3v[nf];
                hl[wv][lq * 4 + r2][nf * 16 + lr] = (_Float16)silu(x);
            }
        __syncthreads();

        f32x4 acc2 = (f32x4){0.f, 0.f, 0.f, 0.f};
        #pragma unroll
        for (int ks = 0; ks < 4; ++ks) {
            const f16x8 a2 = *(const f16x8*)&hl[wv][lr][ks * 32 + lq * 8];
            acc2 = __builtin_amdgcn_mfma_f32_16x16x32_f16(a2, w4f[ks], acc2, 0, 0, 0);
        }
        if (lr < 8) {
            #pragma unroll
            for (int r2 = 0; r2 < 4; ++r2)
                zl[wv][b * 16 + lq * 4 + r2][lr] = acc2[r2] + b4v;
        }
        __syncthreads();
    }

    float z[8];
    {
        float4 z0 = *(const float4*)&zl[wv][lane][0];
        float4 z1 = *(const float4*)&zl[wv][lane][4];
        z[0] = z0.x; z[1] = z0.y; z[2] = z0.z; z[3] = z0.w;
        z[4] = z1.x; z[5] = z1.y; z[6] = z1.z; z[7] = z1.w;
    }
    float m = z[0];
    #pragma unroll
    for (int o = 1; o < 8; ++o) m = fmaxf(m, z[o]);
    float lam[8], den = 0.0f;
    #pragma unroll
    for (int o = 0; o < 8; ++o) { lam[o] = __expf(z[o] - m); den += lam[o]; }
    const float inv = 1.0f / den;
    #pragma unroll
    for (int o = 0; o < 8; ++o) lam[o] *= inv;

    if (n < N) {
        float* orow = out + (size_t)n * 64;
        #pragma unroll
        for (int i = 0; i < 8; ++i) {
            float si[8];
            #pragma unroll
            for (int j = 0; j < 8; ++j) si[j] = lam[j] * V[i * 8 + j];
            float r[8];
            #pragma unroll
            for (int k = 0; k < 8; ++k) {
                float sum = 0.0f;
                #pragma unroll
                for (int j = 0; j < 8; ++j) sum += si[j] * V[k * 8 + j];
                r[k] = sum;
            }
            ((float4*)orow)[i * 2 + 0] = make_float4(r[0], r[1], r[2], r[3]);
            ((float4*)orow)[i * 2 + 1] = make_float4(r[4], r[5], r[6], r[7]);
        }
    }
}

// ---------------------------------------------------------------------------
// Fallback edge kernel (round-2 style, raw fp32 inputs, needs only agg in ws)
// ---------------------------------------------------------------------------
#define CATS 168
#define HS   136
__global__ __launch_bounds__(256, 2)
void k_edge_v2(const float* __restrict__ h_i,
               const float* __restrict__ node_params,
               const float* __restrict__ edge_params,
               const float* __restrict__ W1, const float* __restrict__ b1,
               const float* __restrict__ W2, const float* __restrict__ b2,
               const int* __restrict__ eidx,
               float* __restrict__ agg,
               int N, int E)
{
    __shared__ unsigned short smem[23680];
    unsigned short* w1t = smem;
    unsigned short* w2t = smem + 128 * CATS;
    unsigned short* cat = smem;
    unsigned short* hid = smem + 64 * CATS;

    const int t = threadIdx.x;
    const int lane = t & 63;
    const int wv = t >> 6;
    const int wn = wv & 1;
    const int wm = wv >> 1;
    const int lr = lane & 15;
    const int lq = lane >> 4;

    for (int idx = t; idx < 128 * 80; idx += 256) {
        const int col = idx & 127, kp = idx >> 7;
        const int k0 = 2 * kp;
        float f0 = (k0     < 134) ? W1[(size_t)k0       * 128 + col] : 0.0f;
        float f1 = (k0 + 1 < 134) ? W1[(size_t)(k0 + 1) * 128 + col] : 0.0f;
        *(unsigned*)&w1t[col * CATS + k0] = pack2(f0, f1);
    }
    for (int idx = t; idx < 16 * 64; idx += 256) {
        const int col = idx & 15, kp = idx >> 4;
        const int k0 = 2 * kp;
        *(unsigned*)&w2t[col * HS + k0] =
            pack2(W2[(size_t)k0 * 16 + col], W2[(size_t)(k0 + 1) * 16 + col]);
    }
    __syncthreads();

    bf16x8 bw1[4][5];
    #pragma unroll
    for (int nf = 0; nf < 4; ++nf)
        #pragma unroll
        for (int ks = 0; ks < 5; ++ks)
            bw1[nf][ks] = *(const bf16x8*)&w1t[(wn * 64 + nf * 16 + lr) * CATS + ks * 32 + lq * 8];
    bf16x8 bw2[4];
    #pragma unroll
    for (int ks = 0; ks < 4; ++ks)
        bw2[ks] = *(const bf16x8*)&w2t[lr * HS + ks * 32 + lq * 8];

    float bias1[4];
    #pragma unroll
    for (int nf = 0; nf < 4; ++nf) bias1[nf] = b1[wn * 64 + nf * 16 + lr];
    const float bias2 = b2[lr];
    __syncthreads();

    const int el = t >> 2;
    const int p  = t & 3;

    const int nTiles = E / 64;
    for (int tile = blockIdx.x; tile < nTiles; tile += gridDim.x) {
        const int ebase = tile * 64;
        {
            const int eg  = ebase + el;
            const int egc = (eg < E) ? eg : (E - 1);
            const int s = eidx[egc];
            const int r = eidx[E + egc];
            const float4* hs = (const float4*)(h_i + (size_t)s * 64);
            const float4* hr = (const float4*)(h_i + (size_t)r * 64);
            unsigned short* crow = cat + el * CATS;
            #pragma unroll
            for (int m = 0; m < 8; ++m) {
                const int q = p + 4 * m;
                float4 v = (q < 16) ? hs[q] : hr[q - 16];
                uint2 u; u.x = pack2(v.x, v.y); u.y = pack2(v.z, v.w);
                *(uint2*)&crow[q * 4] = u;
            }
            if (p == 0) {
                const int i0 = eidx[2 * egc];
                const int i1 = eidx[2 * egc + 1];
                uint4 u;
                u.x = pack2(node_params[2 * s], node_params[2 * s + 1]);
                u.y = pack2(node_params[2 * r], node_params[2 * r + 1]);
                u.z = pack2(edge_params[i0], edge_params[i1]);
                u.w = 0u;
                *(uint4*)&crow[128] = u;
            } else {
                uint4 z; z.x = z.y = z.z = z.w = 0u;
                *(uint4*)&crow[136 + (p - 1) * 8] = z;
            }
        }
        __syncthreads();

        f32x4 acc[2][4];
        #pragma unroll
        for (int mf = 0; mf < 2; ++mf)
            #pragma unroll
            for (int nf = 0; nf < 4; ++nf)
                acc[mf][nf] = (f32x4){0.f, 0.f, 0.f, 0.f};

        const unsigned short* pa = cat + (wm * 32 + lr) * CATS + lq * 8;
        #pragma unroll
        for (int ks = 0; ks < 5; ++ks) {
            const bf16x8 a0 = *(const bf16x8*)(pa + ks * 32);
            const bf16x8 a1 = *(const bf16x8*)(pa + 16 * CATS + ks * 32);
            #pragma unroll
            for (int nf = 0; nf < 4; ++nf) {
                acc[0][nf] = __builtin_amdgcn_mfma_f32_16x16x32_bf16(a0, bw1[nf][ks], acc[0][nf], 0, 0, 0);
                acc[1][nf] = __builtin_amdgcn_mfma_f32_16x16x32_bf16(a1, bw1[nf][ks], acc[1][nf], 0, 0, 0);
            }
        }
        __syncthreads();

        #pragma unroll
        for (int mf = 0; mf < 2; ++mf)
            #pragma unroll
            for (int nf = 0; nf < 4; ++nf) {
                const float bb = bias1[nf];
                #pragma unroll
                for (int r2 = 0; r2 < 4; ++r2) {
                    const float x = acc[mf][nf][r2] + bb;
                    hid[(wm * 32 + mf * 16 + lq * 4 + r2) * HS + wn * 64 + nf * 16 + lr] =
                        f2bf(silu(x));
                }
            }
        __syncthreads();

        f32x4 acc2 = (f32x4){0.f, 0.f, 0.f, 0.f};
        const unsigned short* ph = hid + (wv * 16 + lr) * HS + lq * 8;
        #pragma unroll
        for (int ks = 0; ks < 4; ++ks)
            acc2 = __builtin_amdgcn_mfma_f32_16x16x32_bf16(
                *(const bf16x8*)(ph + ks * 32), bw2[ks], acc2, 0, 0, 0);

        #pragma unroll
        for (int r2 = 0; r2 < 4; ++r2) {
            const int eg2 = ebase + wv * 16 + lq * 4 + r2;
            if (eg2 < E) {
                const int rcv = eidx[E + eg2];
                const float v = silu(acc2[r2] + bias2);
                atomicAdd(&agg[(size_t)rcv * 16 + lr], v);
            }
        }
        __syncthreads();
    }
}

// ---------------------------------------------------------------------------
extern "C" void kernel_launch(void* const* d_in, const int* in_sizes, int n_in,
                              void* d_out, int out_size, void* d_ws, size_t ws_size,
                              hipStream_t stream) {
    const float* h_i  = (const float*)d_in[0];
    const float* npar = (const float*)d_in[1];
    const float* epar = (const float*)d_in[2];
    const float* W1   = (const float*)d_in[3];
    const float* b1   = (const float*)d_in[4];
    const float* W2   = (const float*)d_in[5];
    const float* b2   = (const float*)d_in[6];
    const float* W3   = (const float*)d_in[7];
    const float* b3   = (const float*)d_in[8];
    const float* W4   = (const float*)d_in[9];
    const float* b4   = (const float*)d_in[10];
    const int*   eidx = (const int*)d_in[11];

    const int N = in_sizes[0] / 64;
    const int E = in_sizes[11] / 2;

    // workspace layout: agg | SAB(fp16 N x 256) | epk
    const size_t aggB = (size_t)N * 16 * sizeof(float);
    size_t off = (aggB + 255) & ~(size_t)255;
    const size_t sabOff = off;                  off += (size_t)N * 256 * 2;
    off = (off + 255) & ~(size_t)255;
    const size_t epkOff = off;                  off += (size_t)E * 4;
    const size_t need = off;

    float* agg = (float*)d_ws;
    (void)hipMemsetAsync(agg, 0, aggB, stream);

    if (ws_size >= need) {
        unsigned short* SAB = (unsigned short*)((char*)d_ws + sabOff);
        unsigned* epk = (unsigned*)((char*)d_ws + epkOff);

        k_pre2<<<1536, 256, 0, stream>>>(h_i, npar, epar, eidx, W1, b1,
                                         SAB, epk, N, E);
        k_edge_v5<<<2048, 256, 0, stream>>>(SAB, epk, eidx, W1, W2, b2,
                                            agg, N, E);
    } else {
        int blocks = E / 64;
        if (blocks > 768) blocks = 768;
        k_edge_v2<<<blocks, 256, 0, stream>>>(h_i, npar, epar, W1, b1, W2, b2,
                                              eidx, agg, N, E);
    }
    k_node2h<<<(N + 127) / 128, 128, 0, stream>>>(h_i, agg, W3, b3, W4, b4,
                                                  (float*)d_out, N);
}